// Round 12
// baseline (977.581 us; speedup 1.0000x reference)
//
#include <hip/hip_runtime.h>
#include <hip/hip_bf16.h>
#include <hip/hip_cooperative_groups.h>

namespace cg = cooperative_groups;

#define N_ROWS   262144
#define CBLOCKS  256
#define FB_TILES 1024
#define LN_EPS_F 1e-3f
#define EPS_W    1e-8f
#define NEPS_F   (262144.0f*1e-8f)

__device__ __forceinline__ float bf2f(unsigned u){ return __uint_as_float((u&0xffffu)<<16); }
__device__ __forceinline__ unsigned cvtpk(float lo, float hi){
  unsigned r;
  asm("v_cvt_pk_bf16_f32 %0, %1, %2" : "=v"(r) : "v"(lo), "v"(hi));
  return r;
}
__device__ __forceinline__ float wave_sum64(float v){
#pragma unroll
  for (int off=1; off<64; off<<=1) v += __shfl_xor(v, off);
  return v;
}

// ================================================================================
// Cooperative single-kernel path: 256 blocks x 1024 threads, 1 block/CU guaranteed.
// LN once into persistent LDS tiles (4 sub-tiles of 256 rows), then 3 iterations of
// {logits/softmax/numer -> pT -> grid.sync -> update (blocks 0-3) -> grid.sync}.
// ================================================================================
__global__ __launch_bounds__(1024, 4) void slot_kernel(
    const float* __restrict__ x, float* __restrict__ ucoef, float* __restrict__ pT,
    float* __restrict__ slots, float* __restrict__ out_slots, float* __restrict__ attn_out,
    const float* __restrict__ noise_fg, const float* __restrict__ noise_bg,
    const float* __restrict__ mu_fg, const float* __restrict__ ls_fg,
    const float* __restrict__ mu_bg, const float* __restrict__ ls_bg,
    const float* __restrict__ ln_g, const float* __restrict__ ln_b,
    const float* __restrict__ Wk, const float* __restrict__ Wv,
    const float* __restrict__ qfg_g, const float* __restrict__ qfg_b, const float* __restrict__ Wq_fg,
    const float* __restrict__ qbg_g, const float* __restrict__ qbg_b, const float* __restrict__ Wq_bg,
    const float* __restrict__ gfWx, const float* __restrict__ gfWh,
    const float* __restrict__ gfbin, const float* __restrict__ gfbrec,
    const float* __restrict__ gbWx, const float* __restrict__ gbWh,
    const float* __restrict__ gbbin, const float* __restrict__ gbbrec,
    const float* __restrict__ mfg_g, const float* __restrict__ mfg_b,
    const float* __restrict__ mfW1, const float* __restrict__ mfb1,
    const float* __restrict__ mfW2, const float* __restrict__ mfb2,
    const float* __restrict__ mbg_g, const float* __restrict__ mbg_b,
    const float* __restrict__ mbW1, const float* __restrict__ mbb1,
    const float* __restrict__ mbW2, const float* __restrict__ mbb2)
{
  __shared__ __align__(16) ushort xs[4][64*256];   // 128 KB persistent tiles
  __shared__ __align__(16) char scr[17472];        // unioned scratch

  cg::grid_group grid = cg::this_grid();

  const int tid  = threadIdx.x;
  const int wave = tid >> 6, ln = tid & 63;
  const int st   = wave >> 2, w4 = wave & 3;       // sub-tile 0..3, wave-in-subtile 0..3
  const int lm   = ln & 15,  lg = ln >> 4;
  const int blk  = blockIdx.x;
  const int j    = blk;
  const bool upd = (blk < 4);
  const bool bg  = (blk == 0);
  ushort* myxs = xs[st];

  // ---- attn-phase views ----
  uint2* attn_s = (uint2*)scr;                           // [1024]  (8192 B)
  float* qs     = (float*)(scr + 8192);                  // [256]
  float* qc     = (float*)(scr + 9216);                  // [4]
  float (*red)[5][64] = (float(*)[5][64])(scr + 9232);   // [4][5][64] (5120 B)
  float* redc   = (float*)(scr + 14352);                 // [64]
  // ---- update-phase views (time-separated) ----
  float (*pn_s)[64] = (float(*)[64])scr;                 // [8][64]
  float (*pv_s)[64] = (float(*)[64])(scr + 2048);        // [8][64]
  float* csw   = (float*)(scr + 4096);                   // [8]
  float* u_s   = (float*)(scr + 4128);
  float* h_s   = (float*)(scr + 4384);
  float* hg_s  = (float*)(scr + 4640);
  float* l_s   = (float*)(scr + 4896);
  float* vin_s = (float*)(scr + 5152);
  float* ql_s  = (float*)(scr + 5408);
  float (*gxp)[192] = (float(*)[192])(scr + 5664);       // [2][192]
  float (*ghp)[192] = (float(*)[192])(scr + 7200);       // [2][192]
  float* h1_s  = (float*)(scr + 8736);                   // [128]
  float (*p4)[128] = (float(*)[128])(scr + 9248);        // [8][128]
  float (*p16)[64] = (float(*)[64]) (scr + 13344);       // [16][64] -> 17440

  const float* __restrict__ Wx = bg?gbWx:gfWx;  const float* __restrict__ Wh = bg?gbWh:gfWh;
  const float* __restrict__ bi = bg?gbbin:gfbin; const float* __restrict__ br = bg?gbbrec:gfbrec;
  const float* __restrict__ W1 = bg?mbW1:mfW1;  const float* __restrict__ b1 = bg?mbb1:mfb1;
  const float* __restrict__ W2 = bg?mbW2:mfW2;  const float* __restrict__ b2 = bg?mbb2:mfb2;
  const float* __restrict__ Wq = bg?Wq_bg:Wq_fg;
  const float* __restrict__ qg = bg?qbg_g:qfg_g; const float* __restrict__ qb = bg?qbg_b:qfg_b;

  auto q_ucoef = [&](float hn){
    if (tid < 64){
      const float m  = wave_sum64(hn) * (1.f/64.f);
      const float vr = wave_sum64((hn-m)*(hn-m)) * (1.f/64.f);
      const float rs = rsqrtf(vr + LN_EPS_F);
      l_s[tid] = qg[tid]*(hn-m)*rs + qb[tid];
    }
    __syncthreads();
    { const int p = tid >> 6;              // 0..15
      float wq[4];
#pragma unroll
      for (int dd=0; dd<4; ++dd) wq[dd] = Wq[(p*4+dd)*64 + ln];
      float a = 0.f;
#pragma unroll
      for (int dd=0; dd<4; ++dd) a = fmaf(l_s[p*4+dd], wq[dd], a);
      p16[p][ln] = a;
    }
    __syncthreads();
    if (tid < 64){
      float a = 0.f;
#pragma unroll
      for (int p=0; p<16; ++p) a += p16[p][tid];
      ql_s[tid] = a * 0.125f;
    }
    __syncthreads();
    { const int p = tid >> 6;
      float wk[4];
#pragma unroll
      for (int oo=0; oo<4; ++oo) wk[oo] = Wk[ln*64 + p*4 + oo];
      float ts = 0.f;
#pragma unroll
      for (int oo=0; oo<4; ++oo) ts = fmaf(ql_s[p*4+oo], wk[oo], ts);
      p16[p][ln] = ts;
    }
    __syncthreads();
    if (tid < 64){
      float t = 0.f;
#pragma unroll
      for (int p=0; p<16; ++p) t += p16[p][tid];
      ucoef[tid*4 + j] = ln_g[tid]*t;
      const float c = wave_sum64(ln_b[tid]*t);
      if (tid == 0) ucoef[256 + j] = c;
    }
  };

  const size_t r0 = (size_t)blk*1024 + (size_t)st*256;

  // ================= LN once: persistent swizzled tiles =================
#pragma unroll
  for (int mi = 0; mi < 4; ++mi){
    const int trow = w4*64 + mi*16 + lm;
    const float* xr = &x[(r0 + trow)*64 + lg*8];
    const float4 a0 = *(const float4*)xr;
    const float4 a1 = *(const float4*)(xr+4);
    const float4 b0 = *(const float4*)(xr+32);
    const float4 b1 = *(const float4*)(xr+36);
    float s1 = ((a0.x+a0.y)+(a0.z+a0.w)) + ((a1.x+a1.y)+(a1.z+a1.w))
             + ((b0.x+b0.y)+(b0.z+b0.w)) + ((b1.x+b1.y)+(b1.z+b1.w));
    float s2 = a0.x*a0.x; s2=fmaf(a0.y,a0.y,s2); s2=fmaf(a0.z,a0.z,s2); s2=fmaf(a0.w,a0.w,s2);
    s2=fmaf(a1.x,a1.x,s2); s2=fmaf(a1.y,a1.y,s2); s2=fmaf(a1.z,a1.z,s2); s2=fmaf(a1.w,a1.w,s2);
    s2=fmaf(b0.x,b0.x,s2); s2=fmaf(b0.y,b0.y,s2); s2=fmaf(b0.z,b0.z,s2); s2=fmaf(b0.w,b0.w,s2);
    s2=fmaf(b1.x,b1.x,s2); s2=fmaf(b1.y,b1.y,s2); s2=fmaf(b1.z,b1.z,s2); s2=fmaf(b1.w,b1.w,s2);
    s1 += __shfl_xor(s1,16); s2 += __shfl_xor(s2,16);
    s1 += __shfl_xor(s1,32); s2 += __shfl_xor(s2,32);
    const float m  = s1*(1.0f/64.0f);
    const float rs = rsqrtf(s2*(1.0f/64.0f) - m*m + LN_EPS_F);
    const float nm = -m*rs;
    float xv[16];
    xv[0]=fmaf(a0.x,rs,nm); xv[1]=fmaf(a0.y,rs,nm); xv[2]=fmaf(a0.z,rs,nm); xv[3]=fmaf(a0.w,rs,nm);
    xv[4]=fmaf(a1.x,rs,nm); xv[5]=fmaf(a1.y,rs,nm); xv[6]=fmaf(a1.z,rs,nm); xv[7]=fmaf(a1.w,rs,nm);
    xv[8]=fmaf(b0.x,rs,nm); xv[9]=fmaf(b0.y,rs,nm); xv[10]=fmaf(b0.z,rs,nm); xv[11]=fmaf(b0.w,rs,nm);
    xv[12]=fmaf(b1.x,rs,nm); xv[13]=fmaf(b1.y,rs,nm); xv[14]=fmaf(b1.z,rs,nm); xv[15]=fmaf(b1.w,rs,nm);
    const int ch = trow>>3, rr2 = trow&7;
#pragma unroll
    for (int p = 0; p < 8; ++p){
      const int d = lg*8 + p;
      myxs[d*256 + ((ch ^ ((d*5)&31))<<3) + rr2] = (ushort)cvtpk(xv[p], xv[p]);
    }
#pragma unroll
    for (int p = 0; p < 8; ++p){
      const int d = 32 + lg*8 + p;
      myxs[d*256 + ((ch ^ ((d*5)&31))<<3) + rr2] = (ushort)cvtpk(xv[8+p], xv[8+p]);
    }
  }
  __syncthreads();

  // ================= slot init + first ucoef =================
  if (upd){
    float h0 = 0.f;
    if (tid < 64){
      h0 = bg ? fmaf(expf(ls_bg[tid]), noise_bg[tid], mu_bg[tid])
              : fmaf(expf(ls_fg[tid]), noise_fg[(j-1)*64+tid], mu_fg[tid]);
      slots[j*64 + tid] = h0;
    }
    __syncthreads();
    q_ucoef(h0);
  }
  __threadfence();
  grid.sync();

  // ================= 3 iterations =================
  for (int it = 0; it < 3; ++it){
    if (tid < 256) qs[tid] = ucoef[tid];
    else if (tid < 260) qc[tid-256] = ucoef[tid];
    __syncthreads();

    // ---- logits ----
    const int lrow = w4*64 + lm*4;
    float la[4][4] = {};
#pragma unroll
    for (int dd = 0; dd < 16; ++dd){
      const int d = lg*16 + dd;
      const uint2 kk = *(const uint2*)&myxs[d*256 + (((lrow>>3) ^ ((d*5)&31))<<3) + (lrow&7)];
      const float e0 = bf2f(kk.x), e1 = bf2f(kk.x>>16);
      const float e2 = bf2f(kk.y), e3 = bf2f(kk.y>>16);
      const float4 q4 = *(const float4*)&qs[d*4];
#pragma unroll
      for (int s = 0; s < 4; ++s){
        const float qv = (s==0)?q4.x:(s==1)?q4.y:(s==2)?q4.z:q4.w;
        la[0][s] = fmaf(e0, qv, la[0][s]);
        la[1][s] = fmaf(e1, qv, la[1][s]);
        la[2][s] = fmaf(e2, qv, la[2][s]);
        la[3][s] = fmaf(e3, qv, la[3][s]);
      }
    }
#pragma unroll
    for (int r = 0; r < 4; ++r)
#pragma unroll
      for (int s = 0; s < 4; ++s){
        la[r][s] += __shfl_xor(la[r][s], 16);
        la[r][s] += __shfl_xor(la[r][s], 32);
        la[r][s] += qc[s];
      }

    // ---- softmax ----
    float av[4][4];
    float cs0=0.f, cs1=0.f, cs2=0.f, cs3=0.f;
#pragma unroll
    for (int r = 0; r < 4; ++r){
      const float mx = fmaxf(fmaxf(la[r][0],la[r][1]), fmaxf(la[r][2],la[r][3]));
      const float e0 = __expf(la[r][0]-mx), e1 = __expf(la[r][1]-mx);
      const float e2 = __expf(la[r][2]-mx), e3 = __expf(la[r][3]-mx);
      const float inv = 1.0f/((e0+e1)+(e2+e3));
      av[r][0]=e0*inv; av[r][1]=e1*inv; av[r][2]=e2*inv; av[r][3]=e3*inv;
      cs0 += av[r][0]; cs1 += av[r][1]; cs2 += av[r][2]; cs3 += av[r][3];
    }
    if (lg == 0){
#pragma unroll
      for (int r = 0; r < 4; ++r){
        uint2 pk;
        pk.x = cvtpk(av[r][0], av[r][1]);
        pk.y = cvtpk(av[r][2], av[r][3]);
        attn_s[st*256 + lrow + r] = pk;
      }
      if (it == 2){
#pragma unroll
        for (int s = 0; s < 4; ++s){
          float4 o; o.x=av[0][s]; o.y=av[1][s]; o.z=av[2][s]; o.w=av[3][s];
          *(float4*)&attn_out[(size_t)s*N_ROWS + r0 + lrow] = o;
        }
      }
    }
    cs0 = wave_sum64(cs0)*0.25f; cs1 = wave_sum64(cs1)*0.25f;
    cs2 = wave_sum64(cs2)*0.25f; cs3 = wave_sum64(cs3)*0.25f;

    // ---- numer-hat ----
    float n0=0.f,n1=0.f,n2=0.f,n3=0.f, vs=0.f;
#pragma unroll
    for (int rb = 0; rb < 8; ++rb){
      const int ch = w4*8 + rb;
      const uint4 vv = *(const uint4*)&myxs[ln*256 + ((ch ^ ((ln*5)&31))<<3)];
      const ushort* vp = (const ushort*)&vv;
#pragma unroll
      for (int k2 = 0; k2 < 8; ++k2){
        const uint2 au = attn_s[st*256 + ch*8 + k2];
        const float b0v = bf2f(au.x), b1v = bf2f(au.x>>16);
        const float b2v = bf2f(au.y), b3v = bf2f(au.y>>16);
        const float vvv = bf2f((unsigned)vp[k2]);
        n0 = fmaf(b0v, vvv, n0); n1 = fmaf(b1v, vvv, n1);
        n2 = fmaf(b2v, vvv, n2); n3 = fmaf(b3v, vvv, n3);
        vs += vvv;
      }
    }

    // ---- 16-wave reduction -> pT[blk][324] ----
    if (ln == 0){
      redc[wave*4+0]=cs0; redc[wave*4+1]=cs1; redc[wave*4+2]=cs2; redc[wave*4+3]=cs3;
    }
    if (st == 0){
      red[w4][0][ln]=n0; red[w4][1][ln]=n1; red[w4][2][ln]=n2; red[w4][3][ln]=n3; red[w4][4][ln]=vs;
    }
    __syncthreads();
    if (st == 1){
      red[w4][0][ln]+=n0; red[w4][1][ln]+=n1; red[w4][2][ln]+=n2; red[w4][3][ln]+=n3; red[w4][4][ln]+=vs;
    }
    __syncthreads();
    if (st == 2){
      red[w4][0][ln]+=n0; red[w4][1][ln]+=n1; red[w4][2][ln]+=n2; red[w4][3][ln]+=n3; red[w4][4][ln]+=vs;
    }
    __syncthreads();
    if (st == 3){
      red[w4][0][ln]+=n0; red[w4][1][ln]+=n1; red[w4][2][ln]+=n2; red[w4][3][ln]+=n3; red[w4][4][ln]+=vs;
    }
    __syncthreads();
    {
      float* pb = pT + (size_t)blk*324;
      if (tid < 256){
        const int j2 = tid>>6, d = tid&63;
        pb[tid] = (red[0][j2][d]+red[1][j2][d])+(red[2][j2][d]+red[3][j2][d]);
      } else if (tid < 320){
        const int d = tid-256;
        pb[tid] = (red[0][4][d]+red[1][4][d])+(red[2][4][d]+red[3][4][d]);
      } else if (tid < 324){
        const int jj = tid-320;
        float c = 0.f;
#pragma unroll
        for (int w2 = 0; w2 < 16; ++w2) c += redc[w2*4+jj];
        pb[tid] = c;
      }
    }
    __threadfence();
    grid.sync();

    // ================= update (blocks 0-3) =================
    if (upd){
      if (tid < 512){
        const int wv8 = tid>>6;
        float a0=0,a1=0,a2=0, c0=0,c1=0,c2=0;
        for (int bb = 0; bb < 32; bb += 16){
#pragma unroll
          for (int u = 0; u < 16; u += 2){
            const float* pa = pT + (size_t)((bb+u  )*8 + wv8)*324;
            const float* pc = pT + (size_t)((bb+u+1)*8 + wv8)*324;
            a0 += pa[j*64+ln]; a1 += pa[256+ln]; a2 += pa[320+j];
            c0 += pc[j*64+ln]; c1 += pc[256+ln]; c2 += pc[320+j];
          }
        }
        pn_s[wv8][ln] = a0+c0; pv_s[wv8][ln] = a1+c1;
        if (ln == 0) csw[wv8] = a2+c2;
      }
      if (tid < 64) h_s[tid] = slots[j*64 + tid];
      __syncthreads();
      if (tid < 64){
        const float csum = ((csw[0]+csw[1])+(csw[2]+csw[3]))
                         + ((csw[4]+csw[5])+(csw[6]+csw[7])) + NEPS_F;
        float nm = 0.f, vm = 0.f;
#pragma unroll
        for (int p2 = 0; p2 < 8; ++p2){ nm += pn_s[p2][tid]; vm += pv_s[p2][tid]; }
        vin_s[tid] = ln_g[tid]*(nm + EPS_W*vm)/csum + ln_b[tid];
      }
      __syncthreads();
      // u = vin @ Wv (16 partials, chunk-4)
      { const int p = tid >> 6;
        float wv4r[4];
#pragma unroll
        for (int dd=0; dd<4; ++dd) wv4r[dd] = Wv[(p*4+dd)*64 + ln];
        float a = 0.f;
#pragma unroll
        for (int dd=0; dd<4; ++dd) a = fmaf(vin_s[p*4+dd], wv4r[dd], a);
        p16[p][ln] = a;
      }
      __syncthreads();
      if (tid < 64){
        float a = 0.f;
#pragma unroll
        for (int p=0; p<16; ++p) a += p16[p][tid];
        u_s[tid] = a;
      }
      __syncthreads();
      // GRU gates: 4-way split (matrix x half), chunk-16 register staging
      if (tid < 768){
        const int gpart = tid/192, gcol = tid%192;
        const int mtx = gpart>>1, half = gpart&1;
        const float* __restrict__ W = mtx ? Wh : Wx;
        const float* vsrc = mtx ? h_s : u_s;
        float acc = 0.f;
#pragma unroll
        for (int c8 = 0; c8 < 2; ++c8){
          float wr[16];
#pragma unroll
          for (int u2=0; u2<16; ++u2) wr[u2] = W[(half*32 + c8*16+u2)*192 + gcol];
#pragma unroll
          for (int u2=0; u2<16; ++u2) acc = fmaf(vsrc[half*32 + c8*16+u2], wr[u2], acc);
        }
        if (mtx) ghp[half][gcol] = acc; else gxp[half][gcol] = acc;
      }
      __syncthreads();
      if (tid < 64){
        const float gx0 = gxp[0][tid]     + gxp[1][tid]     + bi[tid];
        const float gh0 = ghp[0][tid]     + ghp[1][tid]     + br[tid];
        const float gx1 = gxp[0][64+tid]  + gxp[1][64+tid]  + bi[64+tid];
        const float gh1 = ghp[0][64+tid]  + ghp[1][64+tid]  + br[64+tid];
        const float gx2 = gxp[0][128+tid] + gxp[1][128+tid] + bi[128+tid];
        const float gh2 = ghp[0][128+tid] + ghp[1][128+tid] + br[128+tid];
        const float h  = h_s[tid];
        const float z  = 1.f/(1.f + expf(-(gx0 + gh0)));
        const float rr = 1.f/(1.f + expf(-(gx1 + gh1)));
        const float hc = tanhf(gx2 + rr*gh2);
        const float hg = z*h + (1.f - z)*hc;
        hg_s[tid] = hg;
        const float m  = wave_sum64(hg) * (1.f/64.f);
        const float vr = wave_sum64((hg-m)*(hg-m)) * (1.f/64.f);
        const float rs = rsqrtf(vr + LN_EPS_F);
        l_s[tid] = (bg?mbg_g:mfg_g)[tid]*(hg-m)*rs + (bg?mbg_b:mfg_b)[tid];
      }
      __syncthreads();
      // MLP layer 1 (8 partials, chunk-8)
      { const int p4i = tid >> 7, hi = tid & 127;
        float w1r[8];
#pragma unroll
        for (int dd=0; dd<8; ++dd) w1r[dd] = W1[(p4i*8+dd)*128 + hi];
        float a = 0.f;
#pragma unroll
        for (int dd=0; dd<8; ++dd) a = fmaf(l_s[p4i*8+dd], w1r[dd], a);
        p4[p4i][hi] = a;
      }
      __syncthreads();
      if (tid < 128){
        float a = 0.f;
#pragma unroll
        for (int p=0; p<8; ++p) a += p4[p][tid];
        h1_s[tid] = fmaxf(a + b1[tid], 0.f);
      }
      __syncthreads();
      // MLP layer 2 (16 partials, chunk-8)
      { const int p = tid >> 6;
        float w2r[8];
#pragma unroll
        for (int dd=0; dd<8; ++dd) w2r[dd] = W2[(p*8+dd)*64 + ln];
        float a = 0.f;
#pragma unroll
        for (int dd=0; dd<8; ++dd) a = fmaf(h1_s[p*8+dd], w2r[dd], a);
        p16[p][ln] = a;
      }
      __syncthreads();
      float hnew = 0.f;
      if (tid < 64){
        float a = 0.f;
#pragma unroll
        for (int p=0; p<16; ++p) a += p16[p][tid];
        hnew = hg_s[tid] + b2[tid] + a;
        slots[j*64 + tid] = hnew;
        if (it == 2) out_slots[j*64 + tid] = hnew;
      }
      if (it < 2){
        __syncthreads();
        q_ucoef(hnew);
      }
    }
    if (it < 2){
      __threadfence();
      grid.sync();
    }
  }
}

// ================================================================================
// Fallback path (round-10, verified at 109.7 us): multi-kernel with xhat round-trip.
// ================================================================================
__global__ __launch_bounds__(256) void attn_pass_kernel(
    const float* __restrict__ x, uint* __restrict__ xhat,
    const float* __restrict__ ucoef, float* __restrict__ pT,
    float* __restrict__ attn_out, int first, int last)
{
  __shared__ __align__(16) ushort xs[64*256];
  __shared__ __align__(16) uint2 attn_s[256];
  __shared__ __align__(16) float qs[256];
  __shared__ float qc[4];
  const int tid = threadIdx.x;
  const int w = tid>>6, ln = tid&63;
  const int lm = ln&15, lg = ln>>4;
  qs[tid] = ucoef[tid];
  if (tid < 4) qc[tid] = ucoef[256+tid];

  const size_t r0 = (size_t)blockIdx.x*256;

  if (first){
#pragma unroll
    for (int mi = 0; mi < 4; ++mi){
      const int trow = w*64 + mi*16 + lm;
      const float* xr = &x[(r0 + trow)*64 + lg*8];
      const float4 a0 = *(const float4*)xr;
      const float4 a1 = *(const float4*)(xr+4);
      const float4 b0 = *(const float4*)(xr+32);
      const float4 b1 = *(const float4*)(xr+36);
      float s1 = ((a0.x+a0.y)+(a0.z+a0.w)) + ((a1.x+a1.y)+(a1.z+a1.w))
               + ((b0.x+b0.y)+(b0.z+b0.w)) + ((b1.x+b1.y)+(b1.z+b1.w));
      float s2 = a0.x*a0.x; s2=fmaf(a0.y,a0.y,s2); s2=fmaf(a0.z,a0.z,s2); s2=fmaf(a0.w,a0.w,s2);
      s2=fmaf(a1.x,a1.x,s2); s2=fmaf(a1.y,a1.y,s2); s2=fmaf(a1.z,a1.z,s2); s2=fmaf(a1.w,a1.w,s2);
      s2=fmaf(b0.x,b0.x,s2); s2=fmaf(b0.y,b0.y,s2); s2=fmaf(b0.z,b0.z,s2); s2=fmaf(b0.w,b0.w,s2);
      s2=fmaf(b1.x,b1.x,s2); s2=fmaf(b1.y,b1.y,s2); s2=fmaf(b1.z,b1.z,s2); s2=fmaf(b1.w,b1.w,s2);
      s1 += __shfl_xor(s1,16); s2 += __shfl_xor(s2,16);
      s1 += __shfl_xor(s1,32); s2 += __shfl_xor(s2,32);
      const float m  = s1*(1.0f/64.0f);
      const float rs = rsqrtf(s2*(1.0f/64.0f) - m*m + LN_EPS_F);
      const float nm = -m*rs;
      float xv[16];
      xv[0]=fmaf(a0.x,rs,nm); xv[1]=fmaf(a0.y,rs,nm); xv[2]=fmaf(a0.z,rs,nm); xv[3]=fmaf(a0.w,rs,nm);
      xv[4]=fmaf(a1.x,rs,nm); xv[5]=fmaf(a1.y,rs,nm); xv[6]=fmaf(a1.z,rs,nm); xv[7]=fmaf(a1.w,rs,nm);
      xv[8]=fmaf(b0.x,rs,nm); xv[9]=fmaf(b0.y,rs,nm); xv[10]=fmaf(b0.z,rs,nm); xv[11]=fmaf(b0.w,rs,nm);
      xv[12]=fmaf(b1.x,rs,nm); xv[13]=fmaf(b1.y,rs,nm); xv[14]=fmaf(b1.z,rs,nm); xv[15]=fmaf(b1.w,rs,nm);
      const int ch = trow>>3, rr2 = trow&7;
#pragma unroll
      for (int p = 0; p < 8; ++p){
        const int d = lg*8 + p;
        xs[d*256 + ((ch ^ ((d*5)&31))<<3) + rr2] = (ushort)cvtpk(xv[p], xv[p]);
      }
#pragma unroll
      for (int p = 0; p < 8; ++p){
        const int d = 32 + lg*8 + p;
        xs[d*256 + ((ch ^ ((d*5)&31))<<3) + rr2] = (ushort)cvtpk(xv[8+p], xv[8+p]);
      }
    }
    __syncthreads();
#pragma unroll
    for (int k = 0; k < 8; ++k){
      const int i = k*256 + tid;
      const uint4 v = *(const uint4*)&xs[i*8];
      *(uint4*)&xhat[(size_t)blockIdx.x*8192 + i*4] = v;
    }
  } else {
#pragma unroll
    for (int k = 0; k < 8; ++k){
      const int i = k*256 + tid;
      const uint4 v = *(const uint4*)&xhat[(size_t)blockIdx.x*8192 + i*4];
      *(uint4*)&xs[i*8] = v;
    }
    __syncthreads();
  }

  const int lrow = w*64 + lm*4;
  float la[4][4] = {};
#pragma unroll
  for (int dd = 0; dd < 16; ++dd){
    const int d = lg*16 + dd;
    const uint2 kk = *(const uint2*)&xs[d*256 + (((lrow>>3) ^ ((d*5)&31))<<3) + (lrow&7)];
    const float e0 = bf2f(kk.x), e1 = bf2f(kk.x>>16);
    const float e2 = bf2f(kk.y), e3 = bf2f(kk.y>>16);
    const float4 q4 = *(const float4*)&qs[d*4];
#pragma unroll
    for (int s = 0; s < 4; ++s){
      const float qv = (s==0)?q4.x:(s==1)?q4.y:(s==2)?q4.z:q4.w;
      la[0][s] = fmaf(e0, qv, la[0][s]);
      la[1][s] = fmaf(e1, qv, la[1][s]);
      la[2][s] = fmaf(e2, qv, la[2][s]);
      la[3][s] = fmaf(e3, qv, la[3][s]);
    }
  }
#pragma unroll
  for (int r = 0; r < 4; ++r)
#pragma unroll
    for (int s = 0; s < 4; ++s){
      la[r][s] += __shfl_xor(la[r][s], 16);
      la[r][s] += __shfl_xor(la[r][s], 32);
      la[r][s] += qc[s];
    }

  float av[4][4];
  float cs0=0.f, cs1=0.f, cs2=0.f, cs3=0.f;
#pragma unroll
  for (int r = 0; r < 4; ++r){
    const float mx = fmaxf(fmaxf(la[r][0],la[r][1]), fmaxf(la[r][2],la[r][3]));
    const float e0 = __expf(la[r][0]-mx), e1 = __expf(la[r][1]-mx);
    const float e2 = __expf(la[r][2]-mx), e3 = __expf(la[r][3]-mx);
    const float inv = 1.0f/((e0+e1)+(e2+e3));
    av[r][0]=e0*inv; av[r][1]=e1*inv; av[r][2]=e2*inv; av[r][3]=e3*inv;
    cs0 += av[r][0]; cs1 += av[r][1]; cs2 += av[r][2]; cs3 += av[r][3];
  }
  if (lg == 0){
#pragma unroll
    for (int r = 0; r < 4; ++r){
      uint2 pk;
      pk.x = cvtpk(av[r][0], av[r][1]);
      pk.y = cvtpk(av[r][2], av[r][3]);
      attn_s[lrow + r] = pk;
    }
    if (last){
#pragma unroll
      for (int s = 0; s < 4; ++s){
        float4 o; o.x=av[0][s]; o.y=av[1][s]; o.z=av[2][s]; o.w=av[3][s];
        *(float4*)&attn_out[(size_t)s*N_ROWS + r0 + lrow] = o;
      }
    }
  }
  cs0 = wave_sum64(cs0)*0.25f; cs1 = wave_sum64(cs1)*0.25f;
  cs2 = wave_sum64(cs2)*0.25f; cs3 = wave_sum64(cs3)*0.25f;

  float n0=0.f,n1=0.f,n2=0.f,n3=0.f, vs=0.f;
#pragma unroll
  for (int rb = 0; rb < 8; ++rb){
    const int ch = w*8 + rb;
    const uint4 vv = *(const uint4*)&xs[ln*256 + ((ch ^ ((ln*5)&31))<<3)];
    const ushort* vp = (const ushort*)&vv;
#pragma unroll
    for (int k2 = 0; k2 < 8; ++k2){
      const uint2 au = attn_s[ch*8 + k2];
      const float b0 = bf2f(au.x), b1 = bf2f(au.x>>16);
      const float b2 = bf2f(au.y), b3 = bf2f(au.y>>16);
      const float vvv = bf2f((unsigned)vp[k2]);
      n0 = fmaf(b0, vvv, n0); n1 = fmaf(b1, vvv, n1);
      n2 = fmaf(b2, vvv, n2); n3 = fmaf(b3, vvv, n3);
      vs += vvv;
    }
  }

  __syncthreads();
  float* fp = (float*)xs;
  fp[w*256 + 0*64 + ln] = n0;
  fp[w*256 + 1*64 + ln] = n1;
  fp[w*256 + 2*64 + ln] = n2;
  fp[w*256 + 3*64 + ln] = n3;
  fp[1024 + w*64 + ln] = vs;
  if (ln == 0){ fp[1280+w*4+0]=cs0; fp[1280+w*4+1]=cs1; fp[1280+w*4+2]=cs2; fp[1280+w*4+3]=cs3; }
  __syncthreads();
  float* pb = pT + (size_t)blockIdx.x*324;
  pb[tid] = fp[tid] + fp[256+tid] + fp[512+tid] + fp[768+tid];
  if (tid < 64)
    pb[256 + tid] = fp[1024+tid] + fp[1088+tid] + fp[1152+tid] + fp[1216+tid];
  if (tid < 4)
    pb[320 + tid] = fp[1280+tid] + fp[1284+tid] + fp[1288+tid] + fp[1292+tid];
}

__global__ __launch_bounds__(512) void update_kernel(int mode,
    const float* __restrict__ pT,
    float* __restrict__ slots, float* __restrict__ ucoef, float* __restrict__ out,
    const float* __restrict__ noise_fg, const float* __restrict__ noise_bg,
    const float* __restrict__ mu_fg, const float* __restrict__ ls_fg,
    const float* __restrict__ mu_bg, const float* __restrict__ ls_bg,
    const float* __restrict__ ln_g, const float* __restrict__ ln_b,
    const float* __restrict__ Wk, const float* __restrict__ Wv,
    const float* __restrict__ qfg_g, const float* __restrict__ qfg_b, const float* __restrict__ Wq_fg,
    const float* __restrict__ qbg_g, const float* __restrict__ qbg_b, const float* __restrict__ Wq_bg,
    const float* __restrict__ gfWx, const float* __restrict__ gfWh,
    const float* __restrict__ gfbin, const float* __restrict__ gfbrec,
    const float* __restrict__ gbWx, const float* __restrict__ gbWh,
    const float* __restrict__ gbbin, const float* __restrict__ gbbrec,
    const float* __restrict__ mfg_g, const float* __restrict__ mfg_b,
    const float* __restrict__ mfW1, const float* __restrict__ mfb1,
    const float* __restrict__ mfW2, const float* __restrict__ mfb2,
    const float* __restrict__ mbg_g, const float* __restrict__ mbg_b,
    const float* __restrict__ mbW1, const float* __restrict__ mbb1,
    const float* __restrict__ mbW2, const float* __restrict__ mbb2)
{
  const int j = blockIdx.x;
  const int tid = threadIdx.x;
  const int ln = tid & 63, wv = tid >> 6;
  const bool bg = (j == 0);

  __shared__ __align__(16) float wlds[24640];
  __shared__ float bi_s[192], br_s[192], b1_s[128], b2_s[64];
  __shared__ float mg_s[64], mbv_s[64], qg_s[64], qb_s[64], gl_s[64], bl_s[64];
  __shared__ float vin_s[64], u_s[64], h_s[64], hg_s[64], l_s[64], h1_s[128], ql_s[64];
  __shared__ float gxp[2][192], ghp[2][192];
  __shared__ float pn_s[8][64], pv_s[8][64], csw[8];
  __shared__ float p4[4][128], p8[8][64];

  const float* __restrict__ Wx = bg?gbWx:gfWx;  const float* __restrict__ Wh = bg?gbWh:gfWh;
  const float* __restrict__ bi = bg?gbbin:gfbin; const float* __restrict__ br = bg?gbbrec:gfbrec;
  const float* __restrict__ W1 = bg?mbW1:mfW1;  const float* __restrict__ b1 = bg?mbb1:mfb1;
  const float* __restrict__ W2 = bg?mbW2:mfW2;  const float* __restrict__ b2 = bg?mbb2:mfb2;
  const float* __restrict__ Wq = bg?Wq_bg:Wq_fg;

  const int WQOFF  = (mode == 0) ? 0 : 16384;
  const int WKTOFF = (mode == 0) ? 4096 : 20480;

  float hnew = 0.f;

  if (mode == 0) {
    { const float4* s = (const float4*)Wq; float4* d = (float4*)wlds;
#pragma unroll
      for (int i = 0; i < 2; ++i) d[tid + i*512] = s[tid + i*512]; }
#pragma unroll
    for (int k = 0; k < 8; ++k){
      const int i = tid + k*512;
      wlds[4096 + (i&63)*65 + (i>>6)] = Wk[i];
    }
    if (tid < 64){
      qg_s[tid] = (bg?qbg_g:qfg_g)[tid]; qb_s[tid] = (bg?qbg_b:qfg_b)[tid];
      gl_s[tid] = ln_g[tid]; bl_s[tid] = ln_b[tid];
      hnew = bg ? fmaf(expf(ls_bg[tid]), noise_bg[tid], mu_bg[tid])
                : fmaf(expf(ls_fg[tid]), noise_fg[(j-1)*64+tid], mu_fg[tid]);
      slots[j*64 + tid] = hnew;
    }
    __syncthreads();
  } else {
    if (tid < 192){ bi_s[tid] = bi[tid]; br_s[tid] = br[tid]; }
    else if (tid < 320){ const int i2 = tid-192; b1_s[i2] = b1[i2]; }
    else if (tid < 384){ const int i2 = tid-320; b2_s[i2] = b2[i2]; }
    else if (tid < 448){ const int i2 = tid-384; mg_s[i2] = (bg?mbg_g:mfg_g)[i2]; mbv_s[i2] = (bg?mbg_b:mfg_b)[i2]; }
    else               { const int i2 = tid-448; qg_s[i2] = (bg?qbg_g:qfg_g)[i2]; qb_s[i2] = (bg?qbg_b:qfg_b)[i2]; }
    if (tid < 64){ gl_s[tid] = ln_g[tid]; bl_s[tid] = ln_b[tid]; }
    { const float4* sA = (const float4*)Wx; const float4* sB = (const float4*)Wh;
      float4* dA = (float4*)wlds; float4* dB = (float4*)(wlds + 12288);
#pragma unroll
      for (int i = 0; i < 6; ++i){ dA[tid + i*512] = sA[tid + i*512]; dB[tid + i*512] = sB[tid + i*512]; } }

    {
      float a0 = 0.f, a1 = 0.f, a2 = 0.f;
      float c0 = 0.f, c1v = 0.f, c2v = 0.f;
      for (int bb = 0; bb < FB_TILES/8; bb += 16){
#pragma unroll
        for (int u = 0; u < 16; u += 2){
          const float* pa = pT + (size_t)((bb+u  )*8 + wv)*324;
          const float* pc = pT + (size_t)((bb+u+1)*8 + wv)*324;
          a0 += pa[j*64 + ln];  a1 += pa[256 + ln];  a2 += pa[320 + j];
          c0 += pc[j*64 + ln];  c1v += pc[256 + ln]; c2v += pc[320 + j];
        }
      }
      pn_s[wv][ln] = a0 + c0; pv_s[wv][ln] = a1 + c1v;
      if (ln == 0) csw[wv] = a2 + c2v;
    }
    if (tid < 64) h_s[tid] = slots[j*64 + tid];
    __syncthreads();
    if (tid < 64) {
      const float csum = ((csw[0]+csw[1])+(csw[2]+csw[3])) + ((csw[4]+csw[5])+(csw[6]+csw[7])) + NEPS_F;
      float nm = 0.f, vm = 0.f;
#pragma unroll
      for (int p2 = 0; p2 < 8; ++p2){ nm += pn_s[p2][tid]; vm += pv_s[p2][tid]; }
      vin_s[tid] = gl_s[tid]*(nm + EPS_W*vm)/csum + bl_s[tid];
    }
    __syncthreads();
    { const int p8i = tid >> 6;
      float a = 0.f;
      float wbuf[8];
#pragma unroll
      for (int dd = 0; dd < 8; ++dd) wbuf[dd] = Wv[(p8i*8+dd)*64 + ln];
#pragma unroll
      for (int dd = 0; dd < 8; ++dd) a = fmaf(vin_s[p8i*8+dd], wbuf[dd], a);
      p8[p8i][ln] = a;
    }
    __syncthreads();
    if (tid < 64)
      u_s[tid] = ((p8[0][tid]+p8[1][tid])+(p8[2][tid]+p8[3][tid]))
               + ((p8[4][tid]+p8[5][tid])+(p8[6][tid]+p8[7][tid]));
    __syncthreads();
    if (tid < 384) {
      const int gcol = tid % 192, gp = tid / 192;
      float ax = 0.f, ah = 0.f;
#pragma unroll
      for (int dd = 0; dd < 32; ++dd) {
        ax = fmaf(u_s[gp*32+dd], wlds[(gp*32+dd)*192 + gcol], ax);
        ah = fmaf(h_s[gp*32+dd], wlds[12288 + (gp*32+dd)*192 + gcol], ah);
      }
      gxp[gp][gcol] = ax; ghp[gp][gcol] = ah;
    }
    __syncthreads();
    { const float4* s1 = (const float4*)W1; const float4* s2 = (const float4*)W2; const float4* s3 = (const float4*)Wq;
      float4* d1 = (float4*)wlds; float4* d2 = (float4*)(wlds + 8192); float4* d3 = (float4*)(wlds + 16384);
#pragma unroll
      for (int i = 0; i < 4; ++i){ d1[tid + i*512] = s1[tid + i*512]; d2[tid + i*512] = s2[tid + i*512]; }
#pragma unroll
      for (int i = 0; i < 2; ++i){ d3[tid + i*512] = s3[tid + i*512]; }
#pragma unroll
      for (int k = 0; k < 8; ++k){
        const int i = tid + k*512;
        wlds[20480 + (i&63)*65 + (i>>6)] = Wk[i];
      } }
    if (tid < 64) {
      const float gx0 = gxp[0][tid]     + gxp[1][tid]     + bi_s[tid];
      const float gh0 = ghp[0][tid]     + ghp[1][tid]     + br_s[tid];
      const float gx1 = gxp[0][64+tid]  + gxp[1][64+tid]  + bi_s[64+tid];
      const float gh1 = ghp[0][64+tid]  + ghp[1][64+tid]  + br_s[64+tid];
      const float gx2 = gxp[0][128+tid] + gxp[1][128+tid] + bi_s[128+tid];
      const float gh2 = ghp[0][128+tid] + ghp[1][128+tid] + br_s[128+tid];
      const float h  = h_s[tid];
      const float z  = 1.f/(1.f + expf(-(gx0 + gh0)));
      const float rr = 1.f/(1.f + expf(-(gx1 + gh1)));
      const float hc = tanhf(gx2 + rr*gh2);
      const float hg = z*h + (1.f - z)*hc;
      hg_s[tid] = hg;
      const float m  = wave_sum64(hg) * (1.f/64.f);
      const float vr = wave_sum64((hg-m)*(hg-m)) * (1.f/64.f);
      const float rs = rsqrtf(vr + LN_EPS_F);
      l_s[tid] = mg_s[tid]*(hg-m)*rs + mbv_s[tid];
    }
    __syncthreads();
    { const int p4i = tid >> 7, hi = tid & 127;
      float a = 0.f;
#pragma unroll
      for (int dd = 0; dd < 16; ++dd) a = fmaf(l_s[p4i*16+dd], wlds[(p4i*16+dd)*128 + hi], a);
      p4[p4i][hi] = a;
    }
    __syncthreads();
    if (tid < 128) h1_s[tid] = fmaxf(((p4[0][tid]+p4[1][tid])+(p4[2][tid]+p4[3][tid])) + b1_s[tid], 0.f);
    __syncthreads();
    { const int p8i = tid >> 6;
      float a = 0.f;
#pragma unroll
      for (int dd = 0; dd < 16; ++dd) a = fmaf(h1_s[p8i*16+dd], wlds[8192 + (p8i*16+dd)*64 + ln], a);
      p8[p8i][ln] = a;
    }
    __syncthreads();
    if (tid < 64) {
      hnew = hg_s[tid] + b2_s[tid]
           + ((p8[0][tid]+p8[1][tid])+(p8[2][tid]+p8[3][tid]))
           + ((p8[4][tid]+p8[5][tid])+(p8[6][tid]+p8[7][tid]));
      slots[j*64 + tid] = hnew;
    }
  }

  if (mode == 3) {
    if (tid < 64) out[j*64 + tid] = hnew;
  } else {
    if (tid < 64) {
      const float m  = wave_sum64(hnew) * (1.f/64.f);
      const float vr = wave_sum64((hnew-m)*(hnew-m)) * (1.f/64.f);
      const float rs = rsqrtf(vr + LN_EPS_F);
      l_s[tid] = qg_s[tid]*(hnew-m)*rs + qb_s[tid];
    }
    __syncthreads();
    { const int p8i = tid >> 6;
      float a = 0.f;
#pragma unroll
      for (int dd = 0; dd < 8; ++dd) a = fmaf(l_s[p8i*8+dd], wlds[WQOFF + (p8i*8+dd)*64 + ln], a);
      p8[p8i][ln] = a;
    }
    __syncthreads();
    if (tid < 64)
      ql_s[tid] = (((p8[0][tid]+p8[1][tid])+(p8[2][tid]+p8[3][tid]))
                  +((p8[4][tid]+p8[5][tid])+(p8[6][tid]+p8[7][tid]))) * 0.125f;
    __syncthreads();
    if (tid < 256){
      const int d = tid & 63, pt = tid >> 6;
      float ts = 0.f;
#pragma unroll
      for (int oo = 0; oo < 16; ++oo){
        const int o = pt*16 + oo;
        ts = fmaf(wlds[WKTOFF + o*65 + d], ql_s[o], ts);
      }
      p8[pt][d] = ts;
    }
    __syncthreads();
    if (tid < 64){
      const float t = (p8[0][tid]+p8[1][tid]) + (p8[2][tid]+p8[3][tid]);
      ucoef[tid*4 + j] = gl_s[tid]*t;
      const float c = wave_sum64(bl_s[tid]*t);
      if (tid == 0) ucoef[256 + j] = c;
    }
  }
}

extern "C" void kernel_launch(void* const* d_in, const int* in_sizes, int n_in,
                              void* d_out, int out_size, void* d_ws, size_t ws_size,
                              hipStream_t stream)
{
  const float* x        = (const float*)d_in[0];
  const float* noise_fg = (const float*)d_in[1];
  const float* noise_bg = (const float*)d_in[2];
  const float* ln_g     = (const float*)d_in[3];
  const float* ln_b     = (const float*)d_in[4];
  const float* mu_fg    = (const float*)d_in[5];
  const float* ls_fg    = (const float*)d_in[6];
  const float* mu_bg    = (const float*)d_in[7];
  const float* ls_bg    = (const float*)d_in[8];
  const float* Wk       = (const float*)d_in[9];
  const float* Wv       = (const float*)d_in[10];
  const float* qfg_g    = (const float*)d_in[11];
  const float* qfg_b    = (const float*)d_in[12];
  const float* Wq_fg    = (const float*)d_in[13];
  const float* qbg_g    = (const float*)d_in[14];
  const float* qbg_b    = (const float*)d_in[15];
  const float* Wq_bg    = (const float*)d_in[16];
  const float* gfWx     = (const float*)d_in[17];
  const float* gfWh     = (const float*)d_in[18];
  const float* gfbin    = (const float*)d_in[19];
  const float* gfbrec   = (const float*)d_in[20];
  const float* gbWx     = (const float*)d_in[21];
  const float* gbWh     = (const float*)d_in[22];
  const float* gbbin    = (const float*)d_in[23];
  const float* gbbrec   = (const float*)d_in[24];
  const float* mfg_g    = (const float*)d_in[25];
  const float* mfg_b    = (const float*)d_in[26];
  const float* mfW1     = (const float*)d_in[27];
  const float* mfb1     = (const float*)d_in[28];
  const float* mfW2     = (const float*)d_in[29];
  const float* mfb2     = (const float*)d_in[30];
  const float* mbg_g    = (const float*)d_in[31];
  const float* mbg_b    = (const float*)d_in[32];
  const float* mbW1     = (const float*)d_in[33];
  const float* mbb1     = (const float*)d_in[34];
  const float* mbW2     = (const float*)d_in[35];
  const float* mbb2     = (const float*)d_in[36];

  float* out = (float*)d_out;

  // ws: xhat (32 MB, fallback only) | slots(256) | ucoef(512) | pT(1024*324)
  char* ws = (char*)d_ws;
  uint*  xhat  = (uint*)ws;
  float* fws   = (float*)(ws + (size_t)FB_TILES*8192*4);
  float* slots = fws;
  float* ucoef = fws + 256;
  float* pT    = fws + 1024;
  float* attn_out = out + 256;

  void* args[] = {
    (void*)&x, (void*)&ucoef, (void*)&pT, (void*)&slots, (void*)&out, (void*)&attn_out,
    (void*)&noise_fg, (void*)&noise_bg, (void*)&mu_fg, (void*)&ls_fg,
    (void*)&mu_bg, (void*)&ls_bg, (void*)&ln_g, (void*)&ln_b,
    (void*)&Wk, (void*)&Wv,
    (void*)&qfg_g, (void*)&qfg_b, (void*)&Wq_fg,
    (void*)&qbg_g, (void*)&qbg_b, (void*)&Wq_bg,
    (void*)&gfWx, (void*)&gfWh, (void*)&gfbin, (void*)&gfbrec,
    (void*)&gbWx, (void*)&gbWh, (void*)&gbbin, (void*)&gbbrec,
    (void*)&mfg_g, (void*)&mfg_b, (void*)&mfW1, (void*)&mfb1,
    (void*)&mfW2, (void*)&mfb2,
    (void*)&mbg_g, (void*)&mbg_b, (void*)&mbW1, (void*)&mbb1,
    (void*)&mbW2, (void*)&mbb2
  };
  hipError_t cerr = hipLaunchCooperativeKernel((const void*)slot_kernel,
                                               dim3(CBLOCKS), dim3(1024),
                                               args, 0, stream);
  if (cerr != hipSuccess){
    // -------- fallback: round-10 multi-kernel path (verified) --------
    auto launch_update = [&](int mode){
      update_kernel<<<4, 512, 0, stream>>>(mode, pT, slots, ucoef, out,
        noise_fg, noise_bg, mu_fg, ls_fg, mu_bg, ls_bg, ln_g, ln_b, Wk, Wv,
        qfg_g, qfg_b, Wq_fg, qbg_g, qbg_b, Wq_bg,
        gfWx, gfWh, gfbin, gfbrec, gbWx, gbWh, gbbin, gbbrec,
        mfg_g, mfg_b, mfW1, mfb1, mfW2, mfb2,
        mbg_g, mbg_b, mbW1, mbb1, mbW2, mbb2);
    };
    launch_update(0);
    for (int it = 0; it < 3; ++it) {
      attn_pass_kernel<<<FB_TILES, 256, 0, stream>>>(x, xhat, ucoef, pT, attn_out,
                                                     it==0 ? 1 : 0, it==2 ? 1 : 0);
      launch_update(it+1);
    }
  }
}

// Round 13
// 762.061 us; speedup vs baseline: 1.2828x; 1.2828x over previous
//
#include <hip/hip_runtime.h>
#include <hip/hip_bf16.h>
#include <hip/hip_cooperative_groups.h>

namespace cg = cooperative_groups;

#define N_ROWS   262144
#define CBLOCKS  256
#define FB_TILES 1024
#define LN_EPS_F 1e-3f
#define EPS_W    1e-8f
#define NEPS_F   (262144.0f*1e-8f)

__device__ __forceinline__ float bf2f(unsigned u){ return __uint_as_float((u&0xffffu)<<16); }
__device__ __forceinline__ unsigned cvtpk(float lo, float hi){
  unsigned r;
  asm("v_cvt_pk_bf16_f32 %0, %1, %2" : "=v"(r) : "v"(lo), "v"(hi));
  return r;
}
__device__ __forceinline__ float wave_sum64(float v){
#pragma unroll
  for (int off=1; off<64; off<<=1) v += __shfl_xor(v, off);
  return v;
}

// ================================================================================
// Cooperative single-kernel path: 256 blocks x 512 threads (VGPR cap 256 -> no spill).
// Each block: 1024 rows in 4 persistent LDS sub-tiles (2 waves each). 3 iterations of
// {logits/softmax/numer -> pT -> grid.sync -> update (blocks 0-3) -> grid.sync}.
// ================================================================================
__global__ __launch_bounds__(512, 2) void slot_kernel(
    const float* __restrict__ x, float* __restrict__ ucoef, float* __restrict__ pT,
    float* __restrict__ slots, float* __restrict__ out_slots, float* __restrict__ attn_out,
    const float* __restrict__ noise_fg, const float* __restrict__ noise_bg,
    const float* __restrict__ mu_fg, const float* __restrict__ ls_fg,
    const float* __restrict__ mu_bg, const float* __restrict__ ls_bg,
    const float* __restrict__ ln_g, const float* __restrict__ ln_b,
    const float* __restrict__ Wk, const float* __restrict__ Wv,
    const float* __restrict__ qfg_g, const float* __restrict__ qfg_b, const float* __restrict__ Wq_fg,
    const float* __restrict__ qbg_g, const float* __restrict__ qbg_b, const float* __restrict__ Wq_bg,
    const float* __restrict__ gfWx, const float* __restrict__ gfWh,
    const float* __restrict__ gfbin, const float* __restrict__ gfbrec,
    const float* __restrict__ gbWx, const float* __restrict__ gbWh,
    const float* __restrict__ gbbin, const float* __restrict__ gbbrec,
    const float* __restrict__ mfg_g, const float* __restrict__ mfg_b,
    const float* __restrict__ mfW1, const float* __restrict__ mfb1,
    const float* __restrict__ mfW2, const float* __restrict__ mfb2,
    const float* __restrict__ mbg_g, const float* __restrict__ mbg_b,
    const float* __restrict__ mbW1, const float* __restrict__ mbb1,
    const float* __restrict__ mbW2, const float* __restrict__ mbb2)
{
  __shared__ __align__(16) ushort xs[4][64*256];   // 128 KB persistent tiles
  __shared__ __align__(16) char scr[19616];        // unioned scratch

  cg::grid_group grid = cg::this_grid();

  const int tid  = threadIdx.x;
  const int wave = tid >> 6, ln = tid & 63;
  const int st   = wave >> 1, w2i = wave & 1;      // sub-tile 0..3, wave-in-subtile 0..1
  const int lm   = ln & 15,  lg = ln >> 4;
  const int blk  = blockIdx.x;
  const int j    = blk;
  const bool upd = (blk < 4);
  const bool bg  = (blk == 0);
  ushort* myxs = xs[st];

  // ---- attn-phase views ----
  uint2* attn_s = (uint2*)scr;                           // [1024] 8192 B
  float* qs     = (float*)(scr + 8192);                  // [256]
  float* qc     = (float*)(scr + 9216);                  // [4]
  float (*red)[5][64] = (float(*)[5][64])(scr + 9232);   // [8][5][64] 10240 B
  float* redc   = (float*)(scr + 19472);                 // [32]
  // ---- update-phase views (time-separated) ----
  float (*pn_s)[64] = (float(*)[64])scr;                 // [8][64]
  float (*pv_s)[64] = (float(*)[64])(scr + 2048);        // [8][64]
  float* csw   = (float*)(scr + 4096);                   // [8]
  float* u_s   = (float*)(scr + 4128);
  float* h_s   = (float*)(scr + 4384);
  float* hg_s  = (float*)(scr + 4640);
  float* l_s   = (float*)(scr + 4896);
  float* vin_s = (float*)(scr + 5152);
  float* ql_s  = (float*)(scr + 5408);
  float (*gxp)[192] = (float(*)[192])(scr + 5664);       // [2][192]
  float (*ghp)[192] = (float(*)[192])(scr + 7200);       // [2][192]
  float* h1_s  = (float*)(scr + 8736);                   // [128]
  float (*p4)[128] = (float(*)[128])(scr + 9248);        // [4][128]
  float (*p8)[64]  = (float(*)[64]) (scr + 11296);       // [8][64]

  const float* __restrict__ Wx = bg?gbWx:gfWx;  const float* __restrict__ Wh = bg?gbWh:gfWh;
  const float* __restrict__ bi = bg?gbbin:gfbin; const float* __restrict__ br = bg?gbbrec:gfbrec;
  const float* __restrict__ W1 = bg?mbW1:mfW1;  const float* __restrict__ b1 = bg?mbb1:mfb1;
  const float* __restrict__ W2 = bg?mbW2:mfW2;  const float* __restrict__ b2 = bg?mbb2:mfb2;
  const float* __restrict__ Wq = bg?Wq_bg:Wq_fg;
  const float* __restrict__ qg = bg?qbg_g:qfg_g; const float* __restrict__ qb = bg?qbg_b:qfg_b;

  auto q_ucoef = [&](float hn){
    if (tid < 64){
      const float m  = wave_sum64(hn) * (1.f/64.f);
      const float vr = wave_sum64((hn-m)*(hn-m)) * (1.f/64.f);
      const float rs = rsqrtf(vr + LN_EPS_F);
      l_s[tid] = qg[tid]*(hn-m)*rs + qb[tid];
    }
    __syncthreads();
    { const int p = tid >> 6;              // 0..7
      float wq[8];
#pragma unroll
      for (int dd=0; dd<8; ++dd) wq[dd] = Wq[(p*8+dd)*64 + ln];
      float a = 0.f;
#pragma unroll
      for (int dd=0; dd<8; ++dd) a = fmaf(l_s[p*8+dd], wq[dd], a);
      p8[p][ln] = a;
    }
    __syncthreads();
    if (tid < 64){
      float a = 0.f;
#pragma unroll
      for (int p=0; p<8; ++p) a += p8[p][tid];
      ql_s[tid] = a * 0.125f;
    }
    __syncthreads();
    { const int p = tid >> 6;
      float wk[8];
#pragma unroll
      for (int oo=0; oo<8; ++oo) wk[oo] = Wk[ln*64 + p*8 + oo];
      float ts = 0.f;
#pragma unroll
      for (int oo=0; oo<8; ++oo) ts = fmaf(ql_s[p*8+oo], wk[oo], ts);
      p8[p][ln] = ts;
    }
    __syncthreads();
    if (tid < 64){
      float t = 0.f;
#pragma unroll
      for (int p=0; p<8; ++p) t += p8[p][tid];
      ucoef[tid*4 + j] = ln_g[tid]*t;
      const float c = wave_sum64(ln_b[tid]*t);
      if (tid == 0) ucoef[256 + j] = c;
    }
  };

  const size_t r0 = (size_t)blk*1024 + (size_t)st*256;

  // ================= LN once: persistent swizzled tiles (8 rows-groups/wave) ============
#pragma unroll
  for (int mi = 0; mi < 8; ++mi){
    const int trow = w2i*128 + mi*16 + lm;
    const float* xr = &x[(r0 + trow)*64 + lg*8];
    const float4 a0 = *(const float4*)xr;
    const float4 a1 = *(const float4*)(xr+4);
    const float4 b0 = *(const float4*)(xr+32);
    const float4 b1 = *(const float4*)(xr+36);
    float s1 = ((a0.x+a0.y)+(a0.z+a0.w)) + ((a1.x+a1.y)+(a1.z+a1.w))
             + ((b0.x+b0.y)+(b0.z+b0.w)) + ((b1.x+b1.y)+(b1.z+b1.w));
    float s2 = a0.x*a0.x; s2=fmaf(a0.y,a0.y,s2); s2=fmaf(a0.z,a0.z,s2); s2=fmaf(a0.w,a0.w,s2);
    s2=fmaf(a1.x,a1.x,s2); s2=fmaf(a1.y,a1.y,s2); s2=fmaf(a1.z,a1.z,s2); s2=fmaf(a1.w,a1.w,s2);
    s2=fmaf(b0.x,b0.x,s2); s2=fmaf(b0.y,b0.y,s2); s2=fmaf(b0.z,b0.z,s2); s2=fmaf(b0.w,b0.w,s2);
    s2=fmaf(b1.x,b1.x,s2); s2=fmaf(b1.y,b1.y,s2); s2=fmaf(b1.z,b1.z,s2); s2=fmaf(b1.w,b1.w,s2);
    s1 += __shfl_xor(s1,16); s2 += __shfl_xor(s2,16);
    s1 += __shfl_xor(s1,32); s2 += __shfl_xor(s2,32);
    const float m  = s1*(1.0f/64.0f);
    const float rs = rsqrtf(s2*(1.0f/64.0f) - m*m + LN_EPS_F);
    const float nm = -m*rs;
    float xv[16];
    xv[0]=fmaf(a0.x,rs,nm); xv[1]=fmaf(a0.y,rs,nm); xv[2]=fmaf(a0.z,rs,nm); xv[3]=fmaf(a0.w,rs,nm);
    xv[4]=fmaf(a1.x,rs,nm); xv[5]=fmaf(a1.y,rs,nm); xv[6]=fmaf(a1.z,rs,nm); xv[7]=fmaf(a1.w,rs,nm);
    xv[8]=fmaf(b0.x,rs,nm); xv[9]=fmaf(b0.y,rs,nm); xv[10]=fmaf(b0.z,rs,nm); xv[11]=fmaf(b0.w,rs,nm);
    xv[12]=fmaf(b1.x,rs,nm); xv[13]=fmaf(b1.y,rs,nm); xv[14]=fmaf(b1.z,rs,nm); xv[15]=fmaf(b1.w,rs,nm);
    const int ch = trow>>3, rr2 = trow&7;
#pragma unroll
    for (int p = 0; p < 8; ++p){
      const int d = lg*8 + p;
      myxs[d*256 + ((ch ^ ((d*5)&31))<<3) + rr2] = (ushort)cvtpk(xv[p], xv[p]);
    }
#pragma unroll
    for (int p = 0; p < 8; ++p){
      const int d = 32 + lg*8 + p;
      myxs[d*256 + ((ch ^ ((d*5)&31))<<3) + rr2] = (ushort)cvtpk(xv[8+p], xv[8+p]);
    }
  }
  __syncthreads();

  // ================= slot init + first ucoef =================
  if (upd){
    float h0 = 0.f;
    if (tid < 64){
      h0 = bg ? fmaf(expf(ls_bg[tid]), noise_bg[tid], mu_bg[tid])
              : fmaf(expf(ls_fg[tid]), noise_fg[(j-1)*64+tid], mu_fg[tid]);
      slots[j*64 + tid] = h0;
    }
    __syncthreads();
    q_ucoef(h0);
  }
  __threadfence();
  grid.sync();

  // ================= 3 iterations =================
  for (int it = 0; it < 3; ++it){
    if (tid < 256) qs[tid] = ucoef[tid];
    else if (tid < 260) qc[tid-256] = ucoef[tid];
    __syncthreads();

    float n0=0.f,n1=0.f,n2=0.f,n3=0.f, vs=0.f;
    float cs0=0.f, cs1=0.f, cs2=0.f, cs3=0.f;

#pragma unroll
    for (int h2 = 0; h2 < 2; ++h2){
      // ---- logits: lane owns 4 rows, lg owns a 16-d slice; butterfly over lg ----
      const int lrow = w2i*128 + h2*64 + lm*4;
      float la[4][4] = {};
#pragma unroll
      for (int dd = 0; dd < 16; ++dd){
        const int d = lg*16 + dd;
        const uint2 kk = *(const uint2*)&myxs[d*256 + (((lrow>>3) ^ ((d*5)&31))<<3) + (lrow&7)];
        const float e0 = bf2f(kk.x), e1 = bf2f(kk.x>>16);
        const float e2 = bf2f(kk.y), e3 = bf2f(kk.y>>16);
        const float4 q4 = *(const float4*)&qs[d*4];
#pragma unroll
        for (int s = 0; s < 4; ++s){
          const float qv = (s==0)?q4.x:(s==1)?q4.y:(s==2)?q4.z:q4.w;
          la[0][s] = fmaf(e0, qv, la[0][s]);
          la[1][s] = fmaf(e1, qv, la[1][s]);
          la[2][s] = fmaf(e2, qv, la[2][s]);
          la[3][s] = fmaf(e3, qv, la[3][s]);
        }
      }
#pragma unroll
      for (int r = 0; r < 4; ++r)
#pragma unroll
        for (int s = 0; s < 4; ++s){
          la[r][s] += __shfl_xor(la[r][s], 16);
          la[r][s] += __shfl_xor(la[r][s], 32);
          la[r][s] += qc[s];
        }

      // ---- softmax ----
      float av[4][4];
#pragma unroll
      for (int r = 0; r < 4; ++r){
        const float mx = fmaxf(fmaxf(la[r][0],la[r][1]), fmaxf(la[r][2],la[r][3]));
        const float e0 = __expf(la[r][0]-mx), e1 = __expf(la[r][1]-mx);
        const float e2 = __expf(la[r][2]-mx), e3 = __expf(la[r][3]-mx);
        const float inv = 1.0f/((e0+e1)+(e2+e3));
        av[r][0]=e0*inv; av[r][1]=e1*inv; av[r][2]=e2*inv; av[r][3]=e3*inv;
        cs0 += av[r][0]; cs1 += av[r][1]; cs2 += av[r][2]; cs3 += av[r][3];
      }
      if (lg == 0){
#pragma unroll
        for (int r = 0; r < 4; ++r){
          uint2 pk;
          pk.x = cvtpk(av[r][0], av[r][1]);
          pk.y = cvtpk(av[r][2], av[r][3]);
          attn_s[st*256 + lrow + r] = pk;
        }
        if (it == 2){
#pragma unroll
          for (int s = 0; s < 4; ++s){
            float4 o; o.x=av[0][s]; o.y=av[1][s]; o.z=av[2][s]; o.w=av[3][s];
            *(float4*)&attn_out[(size_t)s*N_ROWS + r0 + lrow] = o;
          }
        }
      }

      // ---- numer-hat over this wave's 64 rows (same-wave attn_s, no barrier) ----
#pragma unroll
      for (int rb = 0; rb < 8; ++rb){
        const int ch = w2i*16 + h2*8 + rb;
        const uint4 vv = *(const uint4*)&myxs[ln*256 + ((ch ^ ((ln*5)&31))<<3)];
        const ushort* vp = (const ushort*)&vv;
#pragma unroll
        for (int k2 = 0; k2 < 8; ++k2){
          const uint2 au = attn_s[st*256 + ch*8 + k2];
          const float b0v = bf2f(au.x), b1v = bf2f(au.x>>16);
          const float b2v = bf2f(au.y), b3v = bf2f(au.y>>16);
          const float vvv = bf2f((unsigned)vp[k2]);
          n0 = fmaf(b0v, vvv, n0); n1 = fmaf(b1v, vvv, n1);
          n2 = fmaf(b2v, vvv, n2); n3 = fmaf(b3v, vvv, n3);
          vs += vvv;
        }
      }
    }
    cs0 = wave_sum64(cs0)*0.25f; cs1 = wave_sum64(cs1)*0.25f;
    cs2 = wave_sum64(cs2)*0.25f; cs3 = wave_sum64(cs3)*0.25f;

    // ---- 8-wave reduction -> pT[blk][324] ----
    if (ln == 0){
      redc[wave*4+0]=cs0; redc[wave*4+1]=cs1; redc[wave*4+2]=cs2; redc[wave*4+3]=cs3;
    }
    red[wave][0][ln]=n0; red[wave][1][ln]=n1; red[wave][2][ln]=n2; red[wave][3][ln]=n3; red[wave][4][ln]=vs;
    __syncthreads();
    {
      float* pb = pT + (size_t)blk*324;
      if (tid < 256){
        const int j2 = tid>>6, d = tid&63;
        float a = 0.f;
#pragma unroll
        for (int w2 = 0; w2 < 8; ++w2) a += red[w2][j2][d];
        pb[tid] = a;
      } else if (tid < 320){
        const int d = tid-256;
        float a = 0.f;
#pragma unroll
        for (int w2 = 0; w2 < 8; ++w2) a += red[w2][4][d];
        pb[tid] = a;
      } else if (tid < 324){
        const int jj = tid-320;
        float c = 0.f;
#pragma unroll
        for (int w2 = 0; w2 < 8; ++w2) c += redc[w2*4+jj];
        pb[tid] = c;
      }
    }
    __threadfence();
    grid.sync();

    // ================= update (blocks 0-3) =================
    if (upd){
      {
        const int wv8 = tid>>6;
        float a0=0,a1=0,a2=0, c0=0,c1=0,c2=0;
        for (int bb = 0; bb < 32; bb += 16){
#pragma unroll
          for (int u = 0; u < 16; u += 2){
            const float* pa = pT + (size_t)((bb+u  )*8 + wv8)*324;
            const float* pc = pT + (size_t)((bb+u+1)*8 + wv8)*324;
            a0 += pa[j*64+ln]; a1 += pa[256+ln]; a2 += pa[320+j];
            c0 += pc[j*64+ln]; c1 += pc[256+ln]; c2 += pc[320+j];
          }
        }
        pn_s[wv8][ln] = a0+c0; pv_s[wv8][ln] = a1+c1;
        if (ln == 0) csw[wv8] = a2+c2;
      }
      if (tid < 64) h_s[tid] = slots[j*64 + tid];
      __syncthreads();
      if (tid < 64){
        const float csum = ((csw[0]+csw[1])+(csw[2]+csw[3]))
                         + ((csw[4]+csw[5])+(csw[6]+csw[7])) + NEPS_F;
        float nm = 0.f, vm = 0.f;
#pragma unroll
        for (int p2 = 0; p2 < 8; ++p2){ nm += pn_s[p2][tid]; vm += pv_s[p2][tid]; }
        vin_s[tid] = ln_g[tid]*(nm + EPS_W*vm)/csum + ln_b[tid];
      }
      __syncthreads();
      // u = vin @ Wv (8 partials, chunk-8)
      { const int p = tid >> 6;
        float wv8r[8];
#pragma unroll
        for (int dd=0; dd<8; ++dd) wv8r[dd] = Wv[(p*8+dd)*64 + ln];
        float a = 0.f;
#pragma unroll
        for (int dd=0; dd<8; ++dd) a = fmaf(vin_s[p*8+dd], wv8r[dd], a);
        p8[p][ln] = a;
      }
      __syncthreads();
      if (tid < 64){
        float a = 0.f;
#pragma unroll
        for (int p=0; p<8; ++p) a += p8[p][tid];
        u_s[tid] = a;
      }
      __syncthreads();
      // GRU gates: 384 threads, full 64-deep, chunk-16 register staging
      if (tid < 384){
        const int gp = tid/192, gcol = tid%192;
        const float* __restrict__ W = gp ? Wh : Wx;
        const float* vsrc = gp ? h_s : u_s;
        float acc = 0.f;
#pragma unroll
        for (int c8 = 0; c8 < 4; ++c8){
          float wr[16];
#pragma unroll
          for (int u2=0; u2<16; ++u2) wr[u2] = W[(c8*16+u2)*192 + gcol];
#pragma unroll
          for (int u2=0; u2<16; ++u2) acc = fmaf(vsrc[c8*16+u2], wr[u2], acc);
        }
        if (gp) ghp[0][gcol] = acc; else gxp[0][gcol] = acc;
      }
      __syncthreads();
      if (tid < 64){
        const float gx0 = gxp[0][tid]     + bi[tid];
        const float gh0 = ghp[0][tid]     + br[tid];
        const float gx1 = gxp[0][64+tid]  + bi[64+tid];
        const float gh1 = ghp[0][64+tid]  + br[64+tid];
        const float gx2 = gxp[0][128+tid] + bi[128+tid];
        const float gh2 = ghp[0][128+tid] + br[128+tid];
        const float h  = h_s[tid];
        const float z  = 1.f/(1.f + expf(-(gx0 + gh0)));
        const float rr = 1.f/(1.f + expf(-(gx1 + gh1)));
        const float hc = tanhf(gx2 + rr*gh2);
        const float hg = z*h + (1.f - z)*hc;
        hg_s[tid] = hg;
        const float m  = wave_sum64(hg) * (1.f/64.f);
        const float vr = wave_sum64((hg-m)*(hg-m)) * (1.f/64.f);
        const float rs = rsqrtf(vr + LN_EPS_F);
        l_s[tid] = (bg?mbg_g:mfg_g)[tid]*(hg-m)*rs + (bg?mbg_b:mfg_b)[tid];
      }
      __syncthreads();
      // MLP layer 1 (4 partials, chunk-16)
      { const int p4i = tid >> 7, hi = tid & 127;
        float w1r[16];
#pragma unroll
        for (int dd=0; dd<16; ++dd) w1r[dd] = W1[(p4i*16+dd)*128 + hi];
        float a = 0.f;
#pragma unroll
        for (int dd=0; dd<16; ++dd) a = fmaf(l_s[p4i*16+dd], w1r[dd], a);
        p4[p4i][hi] = a;
      }
      __syncthreads();
      if (tid < 128){
        float a = (p4[0][tid]+p4[1][tid])+(p4[2][tid]+p4[3][tid]);
        h1_s[tid] = fmaxf(a + b1[tid], 0.f);
      }
      __syncthreads();
      // MLP layer 2 (8 partials, chunk-16)
      { const int p = tid >> 6;
        float w2r[16];
#pragma unroll
        for (int dd=0; dd<16; ++dd) w2r[dd] = W2[(p*16+dd)*64 + ln];
        float a = 0.f;
#pragma unroll
        for (int dd=0; dd<16; ++dd) a = fmaf(h1_s[p*16+dd], w2r[dd], a);
        p8[p][ln] = a;
      }
      __syncthreads();
      float hnew = 0.f;
      if (tid < 64){
        float a = 0.f;
#pragma unroll
        for (int p=0; p<8; ++p) a += p8[p][tid];
        hnew = hg_s[tid] + b2[tid] + a;
        slots[j*64 + tid] = hnew;
        if (it == 2) out_slots[j*64 + tid] = hnew;
      }
      if (it < 2){
        __syncthreads();
        q_ucoef(hnew);
      }
    }
    if (it < 2){
      __threadfence();
      grid.sync();
    }
  }
}

// ================================================================================
// Fallback path (round-10, verified at 109.7 us)
// ================================================================================
__global__ __launch_bounds__(256) void attn_pass_kernel(
    const float* __restrict__ x, uint* __restrict__ xhat,
    const float* __restrict__ ucoef, float* __restrict__ pT,
    float* __restrict__ attn_out, int first, int last)
{
  __shared__ __align__(16) ushort xs[64*256];
  __shared__ __align__(16) uint2 attn_s[256];
  __shared__ __align__(16) float qs[256];
  __shared__ float qc[4];
  const int tid = threadIdx.x;
  const int w = tid>>6, ln = tid&63;
  const int lm = ln&15, lg = ln>>4;
  qs[tid] = ucoef[tid];
  if (tid < 4) qc[tid] = ucoef[256+tid];

  const size_t r0 = (size_t)blockIdx.x*256;

  if (first){
#pragma unroll
    for (int mi = 0; mi < 4; ++mi){
      const int trow = w*64 + mi*16 + lm;
      const float* xr = &x[(r0 + trow)*64 + lg*8];
      const float4 a0 = *(const float4*)xr;
      const float4 a1 = *(const float4*)(xr+4);
      const float4 b0 = *(const float4*)(xr+32);
      const float4 b1 = *(const float4*)(xr+36);
      float s1 = ((a0.x+a0.y)+(a0.z+a0.w)) + ((a1.x+a1.y)+(a1.z+a1.w))
               + ((b0.x+b0.y)+(b0.z+b0.w)) + ((b1.x+b1.y)+(b1.z+b1.w));
      float s2 = a0.x*a0.x; s2=fmaf(a0.y,a0.y,s2); s2=fmaf(a0.z,a0.z,s2); s2=fmaf(a0.w,a0.w,s2);
      s2=fmaf(a1.x,a1.x,s2); s2=fmaf(a1.y,a1.y,s2); s2=fmaf(a1.z,a1.z,s2); s2=fmaf(a1.w,a1.w,s2);
      s2=fmaf(b0.x,b0.x,s2); s2=fmaf(b0.y,b0.y,s2); s2=fmaf(b0.z,b0.z,s2); s2=fmaf(b0.w,b0.w,s2);
      s2=fmaf(b1.x,b1.x,s2); s2=fmaf(b1.y,b1.y,s2); s2=fmaf(b1.z,b1.z,s2); s2=fmaf(b1.w,b1.w,s2);
      s1 += __shfl_xor(s1,16); s2 += __shfl_xor(s2,16);
      s1 += __shfl_xor(s1,32); s2 += __shfl_xor(s2,32);
      const float m  = s1*(1.0f/64.0f);
      const float rs = rsqrtf(s2*(1.0f/64.0f) - m*m + LN_EPS_F);
      const float nm = -m*rs;
      float xv[16];
      xv[0]=fmaf(a0.x,rs,nm); xv[1]=fmaf(a0.y,rs,nm); xv[2]=fmaf(a0.z,rs,nm); xv[3]=fmaf(a0.w,rs,nm);
      xv[4]=fmaf(a1.x,rs,nm); xv[5]=fmaf(a1.y,rs,nm); xv[6]=fmaf(a1.z,rs,nm); xv[7]=fmaf(a1.w,rs,nm);
      xv[8]=fmaf(b0.x,rs,nm); xv[9]=fmaf(b0.y,rs,nm); xv[10]=fmaf(b0.z,rs,nm); xv[11]=fmaf(b0.w,rs,nm);
      xv[12]=fmaf(b1.x,rs,nm); xv[13]=fmaf(b1.y,rs,nm); xv[14]=fmaf(b1.z,rs,nm); xv[15]=fmaf(b1.w,rs,nm);
      const int ch = trow>>3, rr2 = trow&7;
#pragma unroll
      for (int p = 0; p < 8; ++p){
        const int d = lg*8 + p;
        xs[d*256 + ((ch ^ ((d*5)&31))<<3) + rr2] = (ushort)cvtpk(xv[p], xv[p]);
      }
#pragma unroll
      for (int p = 0; p < 8; ++p){
        const int d = 32 + lg*8 + p;
        xs[d*256 + ((ch ^ ((d*5)&31))<<3) + rr2] = (ushort)cvtpk(xv[8+p], xv[8+p]);
      }
    }
    __syncthreads();
#pragma unroll
    for (int k = 0; k < 8; ++k){
      const int i = k*256 + tid;
      const uint4 v = *(const uint4*)&xs[i*8];
      *(uint4*)&xhat[(size_t)blockIdx.x*8192 + i*4] = v;
    }
  } else {
#pragma unroll
    for (int k = 0; k < 8; ++k){
      const int i = k*256 + tid;
      const uint4 v = *(const uint4*)&xhat[(size_t)blockIdx.x*8192 + i*4];
      *(uint4*)&xs[i*8] = v;
    }
    __syncthreads();
  }

  const int lrow = w*64 + lm*4;
  float la[4][4] = {};
#pragma unroll
  for (int dd = 0; dd < 16; ++dd){
    const int d = lg*16 + dd;
    const uint2 kk = *(const uint2*)&xs[d*256 + (((lrow>>3) ^ ((d*5)&31))<<3) + (lrow&7)];
    const float e0 = bf2f(kk.x), e1 = bf2f(kk.x>>16);
    const float e2 = bf2f(kk.y), e3 = bf2f(kk.y>>16);
    const float4 q4 = *(const float4*)&qs[d*4];
#pragma unroll
    for (int s = 0; s < 4; ++s){
      const float qv = (s==0)?q4.x:(s==1)?q4.y:(s==2)?q4.z:q4.w;
      la[0][s] = fmaf(e0, qv, la[0][s]);
      la[1][s] = fmaf(e1, qv, la[1][s]);
      la[2][s] = fmaf(e2, qv, la[2][s]);
      la[3][s] = fmaf(e3, qv, la[3][s]);
    }
  }
#pragma unroll
  for (int r = 0; r < 4; ++r)
#pragma unroll
    for (int s = 0; s < 4; ++s){
      la[r][s] += __shfl_xor(la[r][s], 16);
      la[r][s] += __shfl_xor(la[r][s], 32);
      la[r][s] += qc[s];
    }

  float av[4][4];
  float cs0=0.f, cs1=0.f, cs2=0.f, cs3=0.f;
#pragma unroll
  for (int r = 0; r < 4; ++r){
    const float mx = fmaxf(fmaxf(la[r][0],la[r][1]), fmaxf(la[r][2],la[r][3]));
    const float e0 = __expf(la[r][0]-mx), e1 = __expf(la[r][1]-mx);
    const float e2 = __expf(la[r][2]-mx), e3 = __expf(la[r][3]-mx);
    const float inv = 1.0f/((e0+e1)+(e2+e3));
    av[r][0]=e0*inv; av[r][1]=e1*inv; av[r][2]=e2*inv; av[r][3]=e3*inv;
    cs0 += av[r][0]; cs1 += av[r][1]; cs2 += av[r][2]; cs3 += av[r][3];
  }
  if (lg == 0){
#pragma unroll
    for (int r = 0; r < 4; ++r){
      uint2 pk;
      pk.x = cvtpk(av[r][0], av[r][1]);
      pk.y = cvtpk(av[r][2], av[r][3]);
      attn_s[lrow + r] = pk;
    }
    if (last){
#pragma unroll
      for (int s = 0; s < 4; ++s){
        float4 o; o.x=av[0][s]; o.y=av[1][s]; o.z=av[2][s]; o.w=av[3][s];
        *(float4*)&attn_out[(size_t)s*N_ROWS + r0 + lrow] = o;
      }
    }
  }
  cs0 = wave_sum64(cs0)*0.25f; cs1 = wave_sum64(cs1)*0.25f;
  cs2 = wave_sum64(cs2)*0.25f; cs3 = wave_sum64(cs3)*0.25f;

  float n0=0.f,n1=0.f,n2=0.f,n3=0.f, vs=0.f;
#pragma unroll
  for (int rb = 0; rb < 8; ++rb){
    const int ch = w*8 + rb;
    const uint4 vv = *(const uint4*)&xs[ln*256 + ((ch ^ ((ln*5)&31))<<3)];
    const ushort* vp = (const ushort*)&vv;
#pragma unroll
    for (int k2 = 0; k2 < 8; ++k2){
      const uint2 au = attn_s[ch*8 + k2];
      const float b0 = bf2f(au.x), b1 = bf2f(au.x>>16);
      const float b2 = bf2f(au.y), b3 = bf2f(au.y>>16);
      const float vvv = bf2f((unsigned)vp[k2]);
      n0 = fmaf(b0, vvv, n0); n1 = fmaf(b1, vvv, n1);
      n2 = fmaf(b2, vvv, n2); n3 = fmaf(b3, vvv, n3);
      vs += vvv;
    }
  }

  __syncthreads();
  float* fp = (float*)xs;
  fp[w*256 + 0*64 + ln] = n0;
  fp[w*256 + 1*64 + ln] = n1;
  fp[w*256 + 2*64 + ln] = n2;
  fp[w*256 + 3*64 + ln] = n3;
  fp[1024 + w*64 + ln] = vs;
  if (ln == 0){ fp[1280+w*4+0]=cs0; fp[1280+w*4+1]=cs1; fp[1280+w*4+2]=cs2; fp[1280+w*4+3]=cs3; }
  __syncthreads();
  float* pb = pT + (size_t)blockIdx.x*324;
  pb[tid] = fp[tid] + fp[256+tid] + fp[512+tid] + fp[768+tid];
  if (tid < 64)
    pb[256 + tid] = fp[1024+tid] + fp[1088+tid] + fp[1152+tid] + fp[1216+tid];
  if (tid < 4)
    pb[320 + tid] = fp[1280+tid] + fp[1284+tid] + fp[1288+tid] + fp[1292+tid];
}

__global__ __launch_bounds__(512) void update_kernel(int mode,
    const float* __restrict__ pT,
    float* __restrict__ slots, float* __restrict__ ucoef, float* __restrict__ out,
    const float* __restrict__ noise_fg, const float* __restrict__ noise_bg,
    const float* __restrict__ mu_fg, const float* __restrict__ ls_fg,
    const float* __restrict__ mu_bg, const float* __restrict__ ls_bg,
    const float* __restrict__ ln_g, const float* __restrict__ ln_b,
    const float* __restrict__ Wk, const float* __restrict__ Wv,
    const float* __restrict__ qfg_g, const float* __restrict__ qfg_b, const float* __restrict__ Wq_fg,
    const float* __restrict__ qbg_g, const float* __restrict__ qbg_b, const float* __restrict__ Wq_bg,
    const float* __restrict__ gfWx, const float* __restrict__ gfWh,
    const float* __restrict__ gfbin, const float* __restrict__ gfbrec,
    const float* __restrict__ gbWx, const float* __restrict__ gbWh,
    const float* __restrict__ gbbin, const float* __restrict__ gbbrec,
    const float* __restrict__ mfg_g, const float* __restrict__ mfg_b,
    const float* __restrict__ mfW1, const float* __restrict__ mfb1,
    const float* __restrict__ mfW2, const float* __restrict__ mfb2,
    const float* __restrict__ mbg_g, const float* __restrict__ mbg_b,
    const float* __restrict__ mbW1, const float* __restrict__ mbb1,
    const float* __restrict__ mbW2, const float* __restrict__ mbb2)
{
  const int j = blockIdx.x;
  const int tid = threadIdx.x;
  const int ln = tid & 63, wv = tid >> 6;
  const bool bg = (j == 0);

  __shared__ __align__(16) float wlds[24640];
  __shared__ float bi_s[192], br_s[192], b1_s[128], b2_s[64];
  __shared__ float mg_s[64], mbv_s[64], qg_s[64], qb_s[64], gl_s[64], bl_s[64];
  __shared__ float vin_s[64], u_s[64], h_s[64], hg_s[64], l_s[64], h1_s[128], ql_s[64];
  __shared__ float gxp[2][192], ghp[2][192];
  __shared__ float pn_s[8][64], pv_s[8][64], csw[8];
  __shared__ float p4[4][128], p8[8][64];

  const float* __restrict__ Wx = bg?gbWx:gfWx;  const float* __restrict__ Wh = bg?gbWh:gfWh;
  const float* __restrict__ bi = bg?gbbin:gfbin; const float* __restrict__ br = bg?gbbrec:gfbrec;
  const float* __restrict__ W1 = bg?mbW1:mfW1;  const float* __restrict__ b1 = bg?mbb1:mfb1;
  const float* __restrict__ W2 = bg?mbW2:mfW2;  const float* __restrict__ b2 = bg?mbb2:mfb2;
  const float* __restrict__ Wq = bg?Wq_bg:Wq_fg;

  const int WQOFF  = (mode == 0) ? 0 : 16384;
  const int WKTOFF = (mode == 0) ? 4096 : 20480;

  float hnew = 0.f;

  if (mode == 0) {
    { const float4* s = (const float4*)Wq; float4* d = (float4*)wlds;
#pragma unroll
      for (int i = 0; i < 2; ++i) d[tid + i*512] = s[tid + i*512]; }
#pragma unroll
    for (int k = 0; k < 8; ++k){
      const int i = tid + k*512;
      wlds[4096 + (i&63)*65 + (i>>6)] = Wk[i];
    }
    if (tid < 64){
      qg_s[tid] = (bg?qbg_g:qfg_g)[tid]; qb_s[tid] = (bg?qbg_b:qfg_b)[tid];
      gl_s[tid] = ln_g[tid]; bl_s[tid] = ln_b[tid];
      hnew = bg ? fmaf(expf(ls_bg[tid]), noise_bg[tid], mu_bg[tid])
                : fmaf(expf(ls_fg[tid]), noise_fg[(j-1)*64+tid], mu_fg[tid]);
      slots[j*64 + tid] = hnew;
    }
    __syncthreads();
  } else {
    if (tid < 192){ bi_s[tid] = bi[tid]; br_s[tid] = br[tid]; }
    else if (tid < 320){ const int i2 = tid-192; b1_s[i2] = b1[i2]; }
    else if (tid < 384){ const int i2 = tid-320; b2_s[i2] = b2[i2]; }
    else if (tid < 448){ const int i2 = tid-384; mg_s[i2] = (bg?mbg_g:mfg_g)[i2]; mbv_s[i2] = (bg?mbg_b:mfg_b)[i2]; }
    else               { const int i2 = tid-448; qg_s[i2] = (bg?qbg_g:qfg_g)[i2]; qb_s[i2] = (bg?qbg_b:qfg_b)[i2]; }
    if (tid < 64){ gl_s[tid] = ln_g[tid]; bl_s[tid] = ln_b[tid]; }
    { const float4* sA = (const float4*)Wx; const float4* sB = (const float4*)Wh;
      float4* dA = (float4*)wlds; float4* dB = (float4*)(wlds + 12288);
#pragma unroll
      for (int i = 0; i < 6; ++i){ dA[tid + i*512] = sA[tid + i*512]; dB[tid + i*512] = sB[tid + i*512]; } }

    {
      float a0 = 0.f, a1 = 0.f, a2 = 0.f;
      float c0 = 0.f, c1v = 0.f, c2v = 0.f;
      for (int bb = 0; bb < FB_TILES/8; bb += 16){
#pragma unroll
        for (int u = 0; u < 16; u += 2){
          const float* pa = pT + (size_t)((bb+u  )*8 + wv)*324;
          const float* pc = pT + (size_t)((bb+u+1)*8 + wv)*324;
          a0 += pa[j*64 + ln];  a1 += pa[256 + ln];  a2 += pa[320 + j];
          c0 += pc[j*64 + ln];  c1v += pc[256 + ln]; c2v += pc[320 + j];
        }
      }
      pn_s[wv][ln] = a0 + c0; pv_s[wv][ln] = a1 + c1v;
      if (ln == 0) csw[wv] = a2 + c2v;
    }
    if (tid < 64) h_s[tid] = slots[j*64 + tid];
    __syncthreads();
    if (tid < 64) {
      const float csum = ((csw[0]+csw[1])+(csw[2]+csw[3])) + ((csw[4]+csw[5])+(csw[6]+csw[7])) + NEPS_F;
      float nm = 0.f, vm = 0.f;
#pragma unroll
      for (int p2 = 0; p2 < 8; ++p2){ nm += pn_s[p2][tid]; vm += pv_s[p2][tid]; }
      vin_s[tid] = gl_s[tid]*(nm + EPS_W*vm)/csum + bl_s[tid];
    }
    __syncthreads();
    { const int p8i = tid >> 6;
      float a = 0.f;
      float wbuf[8];
#pragma unroll
      for (int dd = 0; dd < 8; ++dd) wbuf[dd] = Wv[(p8i*8+dd)*64 + ln];
#pragma unroll
      for (int dd = 0; dd < 8; ++dd) a = fmaf(vin_s[p8i*8+dd], wbuf[dd], a);
      p8[p8i][ln] = a;
    }
    __syncthreads();
    if (tid < 64)
      u_s[tid] = ((p8[0][tid]+p8[1][tid])+(p8[2][tid]+p8[3][tid]))
               + ((p8[4][tid]+p8[5][tid])+(p8[6][tid]+p8[7][tid]));
    __syncthreads();
    if (tid < 384) {
      const int gcol = tid % 192, gp = tid / 192;
      float ax = 0.f, ah = 0.f;
#pragma unroll
      for (int dd = 0; dd < 32; ++dd) {
        ax = fmaf(u_s[gp*32+dd], wlds[(gp*32+dd)*192 + gcol], ax);
        ah = fmaf(h_s[gp*32+dd], wlds[12288 + (gp*32+dd)*192 + gcol], ah);
      }
      gxp[gp][gcol] = ax; ghp[gp][gcol] = ah;
    }
    __syncthreads();
    { const float4* s1 = (const float4*)W1; const float4* s2 = (const float4*)W2; const float4* s3 = (const float4*)Wq;
      float4* d1 = (float4*)wlds; float4* d2 = (float4*)(wlds + 8192); float4* d3 = (float4*)(wlds + 16384);
#pragma unroll
      for (int i = 0; i < 4; ++i){ d1[tid + i*512] = s1[tid + i*512]; d2[tid + i*512] = s2[tid + i*512]; }
#pragma unroll
      for (int i = 0; i < 2; ++i){ d3[tid + i*512] = s3[tid + i*512]; }
#pragma unroll
      for (int k = 0; k < 8; ++k){
        const int i = tid + k*512;
        wlds[20480 + (i&63)*65 + (i>>6)] = Wk[i];
      } }
    if (tid < 64) {
      const float gx0 = gxp[0][tid]     + gxp[1][tid]     + bi_s[tid];
      const float gh0 = ghp[0][tid]     + ghp[1][tid]     + br_s[tid];
      const float gx1 = gxp[0][64+tid]  + gxp[1][64+tid]  + bi_s[64+tid];
      const float gh1 = ghp[0][64+tid]  + ghp[1][64+tid]  + br_s[64+tid];
      const float gx2 = gxp[0][128+tid] + gxp[1][128+tid] + bi_s[128+tid];
      const float gh2 = ghp[0][128+tid] + ghp[1][128+tid] + br_s[128+tid];
      const float h  = h_s[tid];
      const float z  = 1.f/(1.f + expf(-(gx0 + gh0)));
      const float rr = 1.f/(1.f + expf(-(gx1 + gh1)));
      const float hc = tanhf(gx2 + rr*gh2);
      const float hg = z*h + (1.f - z)*hc;
      hg_s[tid] = hg;
      const float m  = wave_sum64(hg) * (1.f/64.f);
      const float vr = wave_sum64((hg-m)*(hg-m)) * (1.f/64.f);
      const float rs = rsqrtf(vr + LN_EPS_F);
      l_s[tid] = mg_s[tid]*(hg-m)*rs + mbv_s[tid];
    }
    __syncthreads();
    { const int p4i = tid >> 7, hi = tid & 127;
      float a = 0.f;
#pragma unroll
      for (int dd = 0; dd < 16; ++dd) a = fmaf(l_s[p4i*16+dd], wlds[(p4i*16+dd)*128 + hi], a);
      p4[p4i][hi] = a;
    }
    __syncthreads();
    if (tid < 128) h1_s[tid] = fmaxf(((p4[0][tid]+p4[1][tid])+(p4[2][tid]+p4[3][tid])) + b1_s[tid], 0.f);
    __syncthreads();
    { const int p8i = tid >> 6;
      float a = 0.f;
#pragma unroll
      for (int dd = 0; dd < 16; ++dd) a = fmaf(h1_s[p8i*16+dd], wlds[8192 + (p8i*16+dd)*64 + ln], a);
      p8[p8i][ln] = a;
    }
    __syncthreads();
    if (tid < 64) {
      hnew = hg_s[tid] + b2_s[tid]
           + ((p8[0][tid]+p8[1][tid])+(p8[2][tid]+p8[3][tid]))
           + ((p8[4][tid]+p8[5][tid])+(p8[6][tid]+p8[7][tid]));
      slots[j*64 + tid] = hnew;
    }
  }

  if (mode == 3) {
    if (tid < 64) out[j*64 + tid] = hnew;
  } else {
    if (tid < 64) {
      const float m  = wave_sum64(hnew) * (1.f/64.f);
      const float vr = wave_sum64((hnew-m)*(hnew-m)) * (1.f/64.f);
      const float rs = rsqrtf(vr + LN_EPS_F);
      l_s[tid] = qg_s[tid]*(hnew-m)*rs + qb_s[tid];
    }
    __syncthreads();
    { const int p8i = tid >> 6;
      float a = 0.f;
#pragma unroll
      for (int dd = 0; dd < 8; ++dd) a = fmaf(l_s[p8i*8+dd], wlds[WQOFF + (p8i*8+dd)*64 + ln], a);
      p8[p8i][ln] = a;
    }
    __syncthreads();
    if (tid < 64)
      ql_s[tid] = (((p8[0][tid]+p8[1][tid])+(p8[2][tid]+p8[3][tid]))
                  +((p8[4][tid]+p8[5][tid])+(p8[6][tid]+p8[7][tid]))) * 0.125f;
    __syncthreads();
    if (tid < 256){
      const int d = tid & 63, pt = tid >> 6;
      float ts = 0.f;
#pragma unroll
      for (int oo = 0; oo < 16; ++oo){
        const int o = pt*16 + oo;
        ts = fmaf(wlds[WKTOFF + o*65 + d], ql_s[o], ts);
      }
      p8[pt][d] = ts;
    }
    __syncthreads();
    if (tid < 64){
      const float t = (p8[0][tid]+p8[1][tid]) + (p8[2][tid]+p8[3][tid]);
      ucoef[tid*4 + j] = gl_s[tid]*t;
      const float c = wave_sum64(bl_s[tid]*t);
      if (tid == 0) ucoef[256 + j] = c;
    }
  }
}

extern "C" void kernel_launch(void* const* d_in, const int* in_sizes, int n_in,
                              void* d_out, int out_size, void* d_ws, size_t ws_size,
                              hipStream_t stream)
{
  const float* x        = (const float*)d_in[0];
  const float* noise_fg = (const float*)d_in[1];
  const float* noise_bg = (const float*)d_in[2];
  const float* ln_g     = (const float*)d_in[3];
  const float* ln_b     = (const float*)d_in[4];
  const float* mu_fg    = (const float*)d_in[5];
  const float* ls_fg    = (const float*)d_in[6];
  const float* mu_bg    = (const float*)d_in[7];
  const float* ls_bg    = (const float*)d_in[8];
  const float* Wk       = (const float*)d_in[9];
  const float* Wv       = (const float*)d_in[10];
  const float* qfg_g    = (const float*)d_in[11];
  const float* qfg_b    = (const float*)d_in[12];
  const float* Wq_fg    = (const float*)d_in[13];
  const float* qbg_g    = (const float*)d_in[14];
  const float* qbg_b    = (const float*)d_in[15];
  const float* Wq_bg    = (const float*)d_in[16];
  const float* gfWx     = (const float*)d_in[17];
  const float* gfWh     = (const float*)d_in[18];
  const float* gfbin    = (const float*)d_in[19];
  const float* gfbrec   = (const float*)d_in[20];
  const float* gbWx     = (const float*)d_in[21];
  const float* gbWh     = (const float*)d_in[22];
  const float* gbbin    = (const float*)d_in[23];
  const float* gbbrec   = (const float*)d_in[24];
  const float* mfg_g    = (const float*)d_in[25];
  const float* mfg_b    = (const float*)d_in[26];
  const float* mfW1     = (const float*)d_in[27];
  const float* mfb1     = (const float*)d_in[28];
  const float* mfW2     = (const float*)d_in[29];
  const float* mfb2     = (const float*)d_in[30];
  const float* mbg_g    = (const float*)d_in[31];
  const float* mbg_b    = (const float*)d_in[32];
  const float* mbW1     = (const float*)d_in[33];
  const float* mbb1     = (const float*)d_in[34];
  const float* mbW2     = (const float*)d_in[35];
  const float* mbb2     = (const float*)d_in[36];

  float* out = (float*)d_out;

  // ws: xhat (32 MB, fallback only) | slots(256) | ucoef(512) | pT(1024*324)
  char* ws = (char*)d_ws;
  uint*  xhat  = (uint*)ws;
  float* fws   = (float*)(ws + (size_t)FB_TILES*8192*4);
  float* slots = fws;
  float* ucoef = fws + 256;
  float* pT    = fws + 1024;
  float* attn_out = out + 256;

  void* args[] = {
    (void*)&x, (void*)&ucoef, (void*)&pT, (void*)&slots, (void*)&out, (void*)&attn_out,
    (void*)&noise_fg, (void*)&noise_bg, (void*)&mu_fg, (void*)&ls_fg,
    (void*)&mu_bg, (void*)&ls_bg, (void*)&ln_g, (void*)&ln_b,
    (void*)&Wk, (void*)&Wv,
    (void*)&qfg_g, (void*)&qfg_b, (void*)&Wq_fg,
    (void*)&qbg_g, (void*)&qbg_b, (void*)&Wq_bg,
    (void*)&gfWx, (void*)&gfWh, (void*)&gfbin, (void*)&gfbrec,
    (void*)&gbWx, (void*)&gbWh, (void*)&gbbin, (void*)&gbbrec,
    (void*)&mfg_g, (void*)&mfg_b, (void*)&mfW1, (void*)&mfb1,
    (void*)&mfW2, (void*)&mfb2,
    (void*)&mbg_g, (void*)&mbg_b, (void*)&mbW1, (void*)&mbb1,
    (void*)&mbW2, (void*)&mbb2
  };
  hipError_t cerr = hipLaunchCooperativeKernel((const void*)slot_kernel,
                                               dim3(CBLOCKS), dim3(512),
                                               args, 0, stream);
  if (cerr != hipSuccess){
    // -------- fallback: round-10 multi-kernel path (verified) --------
    auto launch_update = [&](int mode){
      update_kernel<<<4, 512, 0, stream>>>(mode, pT, slots, ucoef, out,
        noise_fg, noise_bg, mu_fg, ls_fg, mu_bg, ls_bg, ln_g, ln_b, Wk, Wv,
        qfg_g, qfg_b, Wq_fg, qbg_g, qbg_b, Wq_bg,
        gfWx, gfWh, gfbin, gfbrec, gbWx, gbWh, gbbin, gbbrec,
        mfg_g, mfg_b, mfW1, mfb1, mfW2, mfb2,
        mbg_g, mbg_b, mbW1, mbb1, mbW2, mbb2);
    };
    launch_update(0);
    for (int it = 0; it < 3; ++it) {
      attn_pass_kernel<<<FB_TILES, 256, 0, stream>>>(x, xhat, ucoef, pT, attn_out,
                                                     it==0 ? 1 : 0, it==2 ? 1 : 0);
      launch_update(it+1);
    }
  }
}

// Round 14
// 109.104 us; speedup vs baseline: 8.9601x; 6.9847x over previous
//
#include <hip/hip_runtime.h>
#include <hip/hip_bf16.h>

#define N_ROWS   262144
#define ATT_BLOCKS 512
#define CHUNKS   2
#define LN_EPS_F 1e-3f
#define EPS_W    1e-8f
#define NEPS_F   (262144.0f*1e-8f)

__device__ __forceinline__ float bf2f(unsigned u){ return __uint_as_float((u&0xffffu)<<16); }
__device__ __forceinline__ unsigned cvtpk(float lo, float hi){
  unsigned r;
  asm("v_cvt_pk_bf16_f32 %0, %1, %2" : "=v"(r) : "v"(lo), "v"(hi));
  return r;
}
__device__ __forceinline__ float wave_sum64(float v){
#pragma unroll
  for (int off=1; off<64; off<<=1) v += __shfl_xor(v, off);
  return v;
}

// ---------- slot-attention pass over x-hat; 512 blocks x 2 chunks of 256 rows ----------
// first=1: LN from x (and per-block redundant prologue computes ucoef; blk0 writes slots).
// else: reload swizzled tile images from xhat with register-staged prefetch.
__global__ __launch_bounds__(256) void attn_pass_kernel(
    const float* __restrict__ x, uint* __restrict__ xhat,
    const float* __restrict__ ucoef, float* __restrict__ pT,
    float* __restrict__ attn_out, float* __restrict__ slots,
    const float* __restrict__ noise_fg, const float* __restrict__ noise_bg,
    const float* __restrict__ mu_fg, const float* __restrict__ ls_fg,
    const float* __restrict__ mu_bg, const float* __restrict__ ls_bg,
    const float* __restrict__ ln_g, const float* __restrict__ ln_b,
    const float* __restrict__ Wk,
    const float* __restrict__ qfg_g, const float* __restrict__ qfg_b, const float* __restrict__ Wq_fg,
    const float* __restrict__ qbg_g, const float* __restrict__ qbg_b, const float* __restrict__ Wq_bg,
    int first, int last)
{
  __shared__ __align__(16) ushort xs[64*256];     // 32 KB swizzled [d][row]
  __shared__ __align__(16) uint2 attn_s[256];
  __shared__ __align__(16) float qs[256];
  __shared__ float qc[4];
  __shared__ float l4[256], q4s[256];
  const int tid = threadIdx.x;
  const int w = tid>>6, ln = tid&63;
  const int lm = ln&15, lg = ln>>4;
  const int blk = blockIdx.x;

  if (first){
    // ---- redundant prologue: slot init -> q -> ucoef (wave w = slot w) ----
    const float h0 = (w==0) ? fmaf(expf(ls_bg[ln]), noise_bg[ln], mu_bg[ln])
                            : fmaf(expf(ls_fg[ln]), noise_fg[(w-1)*64+ln], mu_fg[ln]);
    if (blk == 0) slots[w*64+ln] = h0;
    const float m  = wave_sum64(h0) * (1.f/64.f);
    const float vr = wave_sum64((h0-m)*(h0-m)) * (1.f/64.f);
    const float rs = rsqrtf(vr + LN_EPS_F);
    l4[tid] = (w==0?qbg_g:qfg_g)[ln]*(h0-m)*rs + (w==0?qbg_b:qfg_b)[ln];
    __syncthreads();
    {
      const float* __restrict__ Wqj = (w==0) ? Wq_bg : Wq_fg;
      float acc = 0.f;
#pragma unroll
      for (int dd = 0; dd < 64; ++dd) acc = fmaf(l4[w*64+dd], Wqj[dd*64+ln], acc);
      q4s[tid] = acc * 0.125f;
    }
    __syncthreads();
    {
      float t = 0.f;
#pragma unroll
      for (int oo = 0; oo < 64; ++oo) t = fmaf(Wk[ln*64+oo], q4s[w*64+oo], t);
      qs[ln*4 + w] = ln_g[ln]*t;
      const float cc = wave_sum64(ln_b[ln]*t);
      if (ln == 0) qc[w] = cc;
    }
  } else {
    qs[tid] = ucoef[tid];
    if (tid < 4) qc[tid] = ucoef[256+tid];
  }
  __syncthreads();

  float n0=0.f,n1=0.f,n2=0.f,n3=0.f, vs=0.f;
  float cs0=0.f, cs1=0.f, cs2=0.f, cs3=0.f;

  auto compute_chunk = [&](int c){
    const size_t rg = (size_t)blk*(CHUNKS*256) + (size_t)c*256;
    const int lrow = w*64 + lm*4;
    float la[4][4] = {};
#pragma unroll
    for (int dd = 0; dd < 16; ++dd){
      const int d = lg*16 + dd;
      const uint2 kk = *(const uint2*)&xs[d*256 + (((lrow>>3) ^ ((d*5)&31))<<3) + (lrow&7)];
      const float e0 = bf2f(kk.x), e1 = bf2f(kk.x>>16);
      const float e2 = bf2f(kk.y), e3 = bf2f(kk.y>>16);
      const float4 q4 = *(const float4*)&qs[d*4];
#pragma unroll
      for (int s = 0; s < 4; ++s){
        const float qv = (s==0)?q4.x:(s==1)?q4.y:(s==2)?q4.z:q4.w;
        la[0][s] = fmaf(e0, qv, la[0][s]);
        la[1][s] = fmaf(e1, qv, la[1][s]);
        la[2][s] = fmaf(e2, qv, la[2][s]);
        la[3][s] = fmaf(e3, qv, la[3][s]);
      }
    }
#pragma unroll
    for (int r = 0; r < 4; ++r)
#pragma unroll
      for (int s = 0; s < 4; ++s){
        la[r][s] += __shfl_xor(la[r][s], 16);
        la[r][s] += __shfl_xor(la[r][s], 32);
        la[r][s] += qc[s];
      }
    float av[4][4];
#pragma unroll
    for (int r = 0; r < 4; ++r){
      const float mx = fmaxf(fmaxf(la[r][0],la[r][1]), fmaxf(la[r][2],la[r][3]));
      const float e0 = __expf(la[r][0]-mx), e1 = __expf(la[r][1]-mx);
      const float e2 = __expf(la[r][2]-mx), e3 = __expf(la[r][3]-mx);
      const float inv = 1.0f/((e0+e1)+(e2+e3));
      av[r][0]=e0*inv; av[r][1]=e1*inv; av[r][2]=e2*inv; av[r][3]=e3*inv;
      cs0 += av[r][0]; cs1 += av[r][1]; cs2 += av[r][2]; cs3 += av[r][3];
    }
    if (lg == 0){
#pragma unroll
      for (int r = 0; r < 4; ++r){
        uint2 pk;
        pk.x = cvtpk(av[r][0], av[r][1]);
        pk.y = cvtpk(av[r][2], av[r][3]);
        attn_s[lrow + r] = pk;
      }
      if (last){
#pragma unroll
        for (int s = 0; s < 4; ++s){
          float4 o; o.x=av[0][s]; o.y=av[1][s]; o.z=av[2][s]; o.w=av[3][s];
          *(float4*)&attn_out[(size_t)s*N_ROWS + rg + lrow] = o;
        }
      }
    }
    // numer-hat: thread = dim ln over its wave's 64 rows (wave-local attn_s)
#pragma unroll
    for (int rb = 0; rb < 8; ++rb){
      const int ch = w*8 + rb;
      const uint4 vv = *(const uint4*)&xs[ln*256 + ((ch ^ ((ln*5)&31))<<3)];
      const ushort* vp = (const ushort*)&vv;
#pragma unroll
      for (int k2 = 0; k2 < 8; ++k2){
        const uint2 au = attn_s[ch*8 + k2];
        const float b0 = bf2f(au.x), b1 = bf2f(au.x>>16);
        const float b2 = bf2f(au.y), b3 = bf2f(au.y>>16);
        const float vvv = bf2f((unsigned)vp[k2]);
        n0 = fmaf(b0, vvv, n0); n1 = fmaf(b1, vvv, n1);
        n2 = fmaf(b2, vvv, n2); n3 = fmaf(b3, vvv, n3);
        vs += vvv;
      }
    }
  };

  if (first){
    for (int c = 0; c < CHUNKS; ++c){
      const size_t rg = (size_t)blk*(CHUNKS*256) + (size_t)c*256;
      // ---- LN of 256 rows into swizzled LDS ----
#pragma unroll
      for (int mi = 0; mi < 4; ++mi){
        const int trow = w*64 + mi*16 + lm;
        const float* xr = &x[(rg + trow)*64 + lg*8];
        const float4 a0 = *(const float4*)xr;
        const float4 a1 = *(const float4*)(xr+4);
        const float4 b0 = *(const float4*)(xr+32);
        const float4 b1 = *(const float4*)(xr+36);
        float s1 = ((a0.x+a0.y)+(a0.z+a0.w)) + ((a1.x+a1.y)+(a1.z+a1.w))
                 + ((b0.x+b0.y)+(b0.z+b0.w)) + ((b1.x+b1.y)+(b1.z+b1.w));
        float s2 = a0.x*a0.x; s2=fmaf(a0.y,a0.y,s2); s2=fmaf(a0.z,a0.z,s2); s2=fmaf(a0.w,a0.w,s2);
        s2=fmaf(a1.x,a1.x,s2); s2=fmaf(a1.y,a1.y,s2); s2=fmaf(a1.z,a1.z,s2); s2=fmaf(a1.w,a1.w,s2);
        s2=fmaf(b0.x,b0.x,s2); s2=fmaf(b0.y,b0.y,s2); s2=fmaf(b0.z,b0.z,s2); s2=fmaf(b0.w,b0.w,s2);
        s2=fmaf(b1.x,b1.x,s2); s2=fmaf(b1.y,b1.y,s2); s2=fmaf(b1.z,b1.z,s2); s2=fmaf(b1.w,b1.w,s2);
        s1 += __shfl_xor(s1,16); s2 += __shfl_xor(s2,16);
        s1 += __shfl_xor(s1,32); s2 += __shfl_xor(s2,32);
        const float m  = s1*(1.0f/64.0f);
        const float rs = rsqrtf(s2*(1.0f/64.0f) - m*m + LN_EPS_F);
        const float nm = -m*rs;
        float xv[16];
        xv[0]=fmaf(a0.x,rs,nm); xv[1]=fmaf(a0.y,rs,nm); xv[2]=fmaf(a0.z,rs,nm); xv[3]=fmaf(a0.w,rs,nm);
        xv[4]=fmaf(a1.x,rs,nm); xv[5]=fmaf(a1.y,rs,nm); xv[6]=fmaf(a1.z,rs,nm); xv[7]=fmaf(a1.w,rs,nm);
        xv[8]=fmaf(b0.x,rs,nm); xv[9]=fmaf(b0.y,rs,nm); xv[10]=fmaf(b0.z,rs,nm); xv[11]=fmaf(b0.w,rs,nm);
        xv[12]=fmaf(b1.x,rs,nm); xv[13]=fmaf(b1.y,rs,nm); xv[14]=fmaf(b1.z,rs,nm); xv[15]=fmaf(b1.w,rs,nm);
        const int ch = trow>>3, rr2 = trow&7;
#pragma unroll
        for (int p = 0; p < 8; ++p){
          const int d = lg*8 + p;
          xs[d*256 + ((ch ^ ((d*5)&31))<<3) + rr2] = (ushort)cvtpk(xv[p], xv[p]);
        }
#pragma unroll
        for (int p = 0; p < 8; ++p){
          const int d = 32 + lg*8 + p;
          xs[d*256 + ((ch ^ ((d*5)&31))<<3) + rr2] = (ushort)cvtpk(xv[8+p], xv[8+p]);
        }
      }
      __syncthreads();
      // dump tile image (linear, coalesced; fire-and-forget)
      const size_t tile = (size_t)(blk*CHUNKS + c);
#pragma unroll
      for (int k = 0; k < 8; ++k){
        const int i = k*256 + tid;
        *(uint4*)&xhat[tile*8192 + i*4] = *(const uint4*)&xs[i*8];
      }
      compute_chunk(c);
      __syncthreads();
    }
  } else {
    uint4 sv[8];
    {
      const size_t t0 = (size_t)blk*CHUNKS;
#pragma unroll
      for (int k = 0; k < 8; ++k){ const int i = k*256 + tid; sv[k] = *(const uint4*)&xhat[t0*8192 + i*4]; }
#pragma unroll
      for (int k = 0; k < 8; ++k){ const int i = k*256 + tid; *(uint4*)&xs[i*8] = sv[k]; }
      __syncthreads();
    }
    for (int c = 0; c < CHUNKS; ++c){
      if (c+1 < CHUNKS){
        const size_t tl = (size_t)(blk*CHUNKS + c + 1);
#pragma unroll
        for (int k = 0; k < 8; ++k){ const int i = k*256 + tid; sv[k] = *(const uint4*)&xhat[tl*8192 + i*4]; }
      }
      compute_chunk(c);
      __syncthreads();
      if (c+1 < CHUNKS){
#pragma unroll
        for (int k = 0; k < 8; ++k){ const int i = k*256 + tid; *(uint4*)&xs[i*8] = sv[k]; }
        __syncthreads();
      }
    }
  }

  // ---- block reduction, coalesced pT[blk][324] ----
  cs0 = wave_sum64(cs0)*0.25f; cs1 = wave_sum64(cs1)*0.25f;
  cs2 = wave_sum64(cs2)*0.25f; cs3 = wave_sum64(cs3)*0.25f;
  float* fp = (float*)xs;
  fp[w*256 + 0*64 + ln] = n0;
  fp[w*256 + 1*64 + ln] = n1;
  fp[w*256 + 2*64 + ln] = n2;
  fp[w*256 + 3*64 + ln] = n3;
  fp[1024 + w*64 + ln] = vs;
  if (ln == 0){ fp[1280+w*4+0]=cs0; fp[1280+w*4+1]=cs1; fp[1280+w*4+2]=cs2; fp[1280+w*4+3]=cs3; }
  __syncthreads();
  float* pb = pT + (size_t)blk*324;
  pb[tid] = fp[tid] + fp[256+tid] + fp[512+tid] + fp[768+tid];
  if (tid < 64)
    pb[256 + tid] = fp[1024+tid] + fp[1088+tid] + fp[1152+tid] + fp[1216+tid];
  if (tid < 4)
    pb[320 + tid] = fp[1280+tid] + fp[1284+tid] + fp[1288+tid] + fp[1292+tid];
}

// ---------------- slot update: 4 blocks x 512 threads (round-10 verified) ----------------
__global__ __launch_bounds__(512) void update_kernel(int mode,
    const float* __restrict__ pT,
    float* __restrict__ slots, float* __restrict__ ucoef, float* __restrict__ out,
    const float* __restrict__ ln_g, const float* __restrict__ ln_b,
    const float* __restrict__ Wk, const float* __restrict__ Wv,
    const float* __restrict__ qfg_g, const float* __restrict__ qfg_b, const float* __restrict__ Wq_fg,
    const float* __restrict__ qbg_g, const float* __restrict__ qbg_b, const float* __restrict__ Wq_bg,
    const float* __restrict__ gfWx, const float* __restrict__ gfWh,
    const float* __restrict__ gfbin, const float* __restrict__ gfbrec,
    const float* __restrict__ gbWx, const float* __restrict__ gbWh,
    const float* __restrict__ gbbin, const float* __restrict__ gbbrec,
    const float* __restrict__ mfg_g, const float* __restrict__ mfg_b,
    const float* __restrict__ mfW1, const float* __restrict__ mfb1,
    const float* __restrict__ mfW2, const float* __restrict__ mfb2,
    const float* __restrict__ mbg_g, const float* __restrict__ mbg_b,
    const float* __restrict__ mbW1, const float* __restrict__ mbb1,
    const float* __restrict__ mbW2, const float* __restrict__ mbb2)
{
  const int j = blockIdx.x;
  const int tid = threadIdx.x;
  const int ln = tid & 63, wv = tid >> 6;
  const bool bg = (j == 0);

  __shared__ __align__(16) float wlds[24640];
  __shared__ float bi_s[192], br_s[192], b1_s[128], b2_s[64];
  __shared__ float mg_s[64], mbv_s[64], qg_s[64], qb_s[64], gl_s[64], bl_s[64];
  __shared__ float vin_s[64], u_s[64], h_s[64], hg_s[64], l_s[64], h1_s[128], ql_s[64];
  __shared__ float gxp[2][192], ghp[2][192];
  __shared__ float pn_s[8][64], pv_s[8][64], csw[8];
  __shared__ float p4[4][128], p8[8][64];

  const float* __restrict__ Wx = bg?gbWx:gfWx;  const float* __restrict__ Wh = bg?gbWh:gfWh;
  const float* __restrict__ bi = bg?gbbin:gfbin; const float* __restrict__ br = bg?gbbrec:gfbrec;
  const float* __restrict__ W1 = bg?mbW1:mfW1;  const float* __restrict__ b1 = bg?mbb1:mfb1;
  const float* __restrict__ W2 = bg?mbW2:mfW2;  const float* __restrict__ b2 = bg?mbb2:mfb2;
  const float* __restrict__ Wq = bg?Wq_bg:Wq_fg;

  float hnew = 0.f;

  // ---- parallel staging: biases/params + Wx/Wh ----
  if (tid < 192){ bi_s[tid] = bi[tid]; br_s[tid] = br[tid]; }
  else if (tid < 320){ const int i2 = tid-192; b1_s[i2] = b1[i2]; }
  else if (tid < 384){ const int i2 = tid-320; b2_s[i2] = b2[i2]; }
  else if (tid < 448){ const int i2 = tid-384; mg_s[i2] = (bg?mbg_g:mfg_g)[i2]; mbv_s[i2] = (bg?mbg_b:mfg_b)[i2]; }
  else               { const int i2 = tid-448; qg_s[i2] = (bg?qbg_g:qfg_g)[i2]; qb_s[i2] = (bg?qbg_b:qfg_b)[i2]; }
  if (tid < 64){ gl_s[tid] = ln_g[tid]; bl_s[tid] = ln_b[tid]; }
  { const float4* sA = (const float4*)Wx; const float4* sB = (const float4*)Wh;
    float4* dA = (float4*)wlds; float4* dB = (float4*)(wlds + 12288);
#pragma unroll
    for (int i = 0; i < 6; ++i){ dA[tid + i*512] = sA[tid + i*512]; dB[tid + i*512] = sB[tid + i*512]; } }

  // ---- fused grid-reduce over 512 pT blocks (deep unroll) ----
  {
    float a0 = 0.f, a1 = 0.f, a2 = 0.f;
    float c0 = 0.f, c1v = 0.f, c2v = 0.f;
    for (int bb = 0; bb < ATT_BLOCKS/8; bb += 16){
#pragma unroll
      for (int u = 0; u < 16; u += 2){
        const float* pa = pT + (size_t)((bb+u  )*8 + wv)*324;
        const float* pc = pT + (size_t)((bb+u+1)*8 + wv)*324;
        a0 += pa[j*64 + ln];  a1 += pa[256 + ln];  a2 += pa[320 + j];
        c0 += pc[j*64 + ln];  c1v += pc[256 + ln]; c2v += pc[320 + j];
      }
    }
    pn_s[wv][ln] = a0 + c0; pv_s[wv][ln] = a1 + c1v;
    if (ln == 0) csw[wv] = a2 + c2v;
  }
  if (tid < 64) h_s[tid] = slots[j*64 + tid];
  __syncthreads();
  if (tid < 64) {
    const float csum = ((csw[0]+csw[1])+(csw[2]+csw[3])) + ((csw[4]+csw[5])+(csw[6]+csw[7])) + NEPS_F;
    float nm = 0.f, vm = 0.f;
#pragma unroll
    for (int p2 = 0; p2 < 8; ++p2){ nm += pn_s[p2][tid]; vm += pv_s[p2][tid]; }
    vin_s[tid] = gl_s[tid]*(nm + EPS_W*vm)/csum + bl_s[tid];
  }
  __syncthreads();
  // u = vin @ Wv
  { const int p8i = tid >> 6;
    float a = 0.f;
    float wbuf[8];
#pragma unroll
    for (int dd = 0; dd < 8; ++dd) wbuf[dd] = Wv[(p8i*8+dd)*64 + ln];
#pragma unroll
    for (int dd = 0; dd < 8; ++dd) a = fmaf(vin_s[p8i*8+dd], wbuf[dd], a);
    p8[p8i][ln] = a;
  }
  __syncthreads();
  if (tid < 64)
    u_s[tid] = ((p8[0][tid]+p8[1][tid])+(p8[2][tid]+p8[3][tid]))
             + ((p8[4][tid]+p8[5][tid])+(p8[6][tid]+p8[7][tid]));
  __syncthreads();
  // GRU gates gemv (LDS weights)
  if (tid < 384) {
    const int gcol = tid % 192, gp = tid / 192;
    float ax = 0.f, ah = 0.f;
#pragma unroll
    for (int dd = 0; dd < 32; ++dd) {
      ax = fmaf(u_s[gp*32+dd], wlds[(gp*32+dd)*192 + gcol], ax);
      ah = fmaf(h_s[gp*32+dd], wlds[12288 + (gp*32+dd)*192 + gcol], ah);
    }
    gxp[gp][gcol] = ax; ghp[gp][gcol] = ah;
  }
  __syncthreads();
  // stage B: W1, W2, Wq, WkT
  { const float4* s1 = (const float4*)W1; const float4* s2 = (const float4*)W2; const float4* s3 = (const float4*)Wq;
    float4* d1 = (float4*)wlds; float4* d2 = (float4*)(wlds + 8192); float4* d3 = (float4*)(wlds + 16384);
#pragma unroll
    for (int i = 0; i < 4; ++i){ d1[tid + i*512] = s1[tid + i*512]; d2[tid + i*512] = s2[tid + i*512]; }
#pragma unroll
    for (int i = 0; i < 2; ++i){ d3[tid + i*512] = s3[tid + i*512]; }
#pragma unroll
    for (int k = 0; k < 8; ++k){
      const int i = tid + k*512;
      wlds[20480 + (i&63)*65 + (i>>6)] = Wk[i];
    } }
  if (tid < 64) {
    const float gx0 = gxp[0][tid]     + gxp[1][tid]     + bi_s[tid];
    const float gh0 = ghp[0][tid]     + ghp[1][tid]     + br_s[tid];
    const float gx1 = gxp[0][64+tid]  + gxp[1][64+tid]  + bi_s[64+tid];
    const float gh1 = ghp[0][64+tid]  + ghp[1][64+tid]  + br_s[64+tid];
    const float gx2 = gxp[0][128+tid] + gxp[1][128+tid] + bi_s[128+tid];
    const float gh2 = ghp[0][128+tid] + ghp[1][128+tid] + br_s[128+tid];
    const float h  = h_s[tid];
    const float z  = 1.f/(1.f + expf(-(gx0 + gh0)));
    const float rr = 1.f/(1.f + expf(-(gx1 + gh1)));
    const float hc = tanhf(gx2 + rr*gh2);
    const float hg = z*h + (1.f - z)*hc;
    hg_s[tid] = hg;
    const float m  = wave_sum64(hg) * (1.f/64.f);
    const float vr = wave_sum64((hg-m)*(hg-m)) * (1.f/64.f);
    const float rs = rsqrtf(vr + LN_EPS_F);
    l_s[tid] = mg_s[tid]*(hg-m)*rs + mbv_s[tid];
  }
  __syncthreads();
  { const int p4i = tid >> 7, hi = tid & 127;
    float a = 0.f;
#pragma unroll
    for (int dd = 0; dd < 16; ++dd) a = fmaf(l_s[p4i*16+dd], wlds[(p4i*16+dd)*128 + hi], a);
    p4[p4i][hi] = a;
  }
  __syncthreads();
  if (tid < 128) h1_s[tid] = fmaxf(((p4[0][tid]+p4[1][tid])+(p4[2][tid]+p4[3][tid])) + b1_s[tid], 0.f);
  __syncthreads();
  { const int p8i = tid >> 6;
    float a = 0.f;
#pragma unroll
    for (int dd = 0; dd < 16; ++dd) a = fmaf(h1_s[p8i*16+dd], wlds[8192 + (p8i*16+dd)*64 + ln], a);
    p8[p8i][ln] = a;
  }
  __syncthreads();
  if (tid < 64) {
    hnew = hg_s[tid] + b2_s[tid]
         + ((p8[0][tid]+p8[1][tid])+(p8[2][tid]+p8[3][tid]))
         + ((p8[4][tid]+p8[5][tid])+(p8[6][tid]+p8[7][tid]));
    slots[j*64 + tid] = hnew;
  }

  if (mode == 3) {
    if (tid < 64) out[j*64 + tid] = hnew;
  } else {
    if (tid < 64) {
      const float m  = wave_sum64(hnew) * (1.f/64.f);
      const float vr = wave_sum64((hnew-m)*(hnew-m)) * (1.f/64.f);
      const float rs = rsqrtf(vr + LN_EPS_F);
      l_s[tid] = qg_s[tid]*(hnew-m)*rs + qb_s[tid];
    }
    __syncthreads();
    { const int p8i = tid >> 6;
      float a = 0.f;
#pragma unroll
      for (int dd = 0; dd < 8; ++dd) a = fmaf(l_s[p8i*8+dd], wlds[16384 + (p8i*8+dd)*64 + ln], a);
      p8[p8i][ln] = a;
    }
    __syncthreads();
    if (tid < 64)
      ql_s[tid] = (((p8[0][tid]+p8[1][tid])+(p8[2][tid]+p8[3][tid]))
                  +((p8[4][tid]+p8[5][tid])+(p8[6][tid]+p8[7][tid]))) * 0.125f;
    __syncthreads();
    if (tid < 256){
      const int d = tid & 63, pt = tid >> 6;
      float ts = 0.f;
#pragma unroll
      for (int oo = 0; oo < 16; ++oo){
        const int o = pt*16 + oo;
        ts = fmaf(wlds[20480 + o*65 + d], ql_s[o], ts);
      }
      p8[pt][d] = ts;
    }
    __syncthreads();
    if (tid < 64){
      const float t = (p8[0][tid]+p8[1][tid]) + (p8[2][tid]+p8[3][tid]);
      ucoef[tid*4 + j] = gl_s[tid]*t;
      const float c = wave_sum64(bl_s[tid]*t);
      if (tid == 0) ucoef[256 + j] = c;
    }
  }
}

extern "C" void kernel_launch(void* const* d_in, const int* in_sizes, int n_in,
                              void* d_out, int out_size, void* d_ws, size_t ws_size,
                              hipStream_t stream)
{
  const float* x        = (const float*)d_in[0];
  const float* noise_fg = (const float*)d_in[1];
  const float* noise_bg = (const float*)d_in[2];
  const float* ln_g     = (const float*)d_in[3];
  const float* ln_b     = (const float*)d_in[4];
  const float* mu_fg    = (const float*)d_in[5];
  const float* ls_fg    = (const float*)d_in[6];
  const float* mu_bg    = (const float*)d_in[7];
  const float* ls_bg    = (const float*)d_in[8];
  const float* Wk       = (const float*)d_in[9];
  const float* Wv       = (const float*)d_in[10];
  const float* qfg_g    = (const float*)d_in[11];
  const float* qfg_b    = (const float*)d_in[12];
  const float* Wq_fg    = (const float*)d_in[13];
  const float* qbg_g    = (const float*)d_in[14];
  const float* qbg_b    = (const float*)d_in[15];
  const float* Wq_bg    = (const float*)d_in[16];
  const float* gfWx     = (const float*)d_in[17];
  const float* gfWh     = (const float*)d_in[18];
  const float* gfbin    = (const float*)d_in[19];
  const float* gfbrec   = (const float*)d_in[20];
  const float* gbWx     = (const float*)d_in[21];
  const float* gbWh     = (const float*)d_in[22];
  const float* gbbin    = (const float*)d_in[23];
  const float* gbbrec   = (const float*)d_in[24];
  const float* mfg_g    = (const float*)d_in[25];
  const float* mfg_b    = (const float*)d_in[26];
  const float* mfW1     = (const float*)d_in[27];
  const float* mfb1     = (const float*)d_in[28];
  const float* mfW2     = (const float*)d_in[29];
  const float* mfb2     = (const float*)d_in[30];
  const float* mbg_g    = (const float*)d_in[31];
  const float* mbg_b    = (const float*)d_in[32];
  const float* mbW1     = (const float*)d_in[33];
  const float* mbb1     = (const float*)d_in[34];
  const float* mbW2     = (const float*)d_in[35];
  const float* mbb2     = (const float*)d_in[36];

  float* out = (float*)d_out;

  // ws: xhat (32 MB tile images) | slots(256) | ucoef(512) | pT(512*324)
  char* ws = (char*)d_ws;
  uint*  xhat  = (uint*)ws;
  float* fws   = (float*)(ws + (size_t)ATT_BLOCKS*CHUNKS*8192*4);
  float* slots = fws;
  float* ucoef = fws + 256;
  float* pT    = fws + 1024;
  float* attn_out = out + 256;

  auto launch_attn = [&](int first, int last){
    attn_pass_kernel<<<ATT_BLOCKS, 256, 0, stream>>>(x, xhat, ucoef, pT, attn_out, slots,
      noise_fg, noise_bg, mu_fg, ls_fg, mu_bg, ls_bg, ln_g, ln_b, Wk,
      qfg_g, qfg_b, Wq_fg, qbg_g, qbg_b, Wq_bg, first, last);
  };
  auto launch_update = [&](int mode){
    update_kernel<<<4, 512, 0, stream>>>(mode, pT, slots, ucoef, out,
      ln_g, ln_b, Wk, Wv,
      qfg_g, qfg_b, Wq_fg, qbg_g, qbg_b, Wq_bg,
      gfWx, gfWh, gfbin, gfbrec, gbWx, gbWh, gbbin, gbbrec,
      mfg_g, mfg_b, mfW1, mfb1, mfW2, mfb2,
      mbg_g, mbg_b, mbW1, mbb1, mbW2, mbb2);
  };

  launch_attn(1, 0);
  launch_update(1);
  launch_attn(0, 0);
  launch_update(2);
  launch_attn(0, 1);
  launch_update(3);
}